// Round 2
// baseline (6524.675 us; speedup 1.0000x reference)
//
#include <hip/hip_runtime.h>
#include <math.h>

// SAConvLSTM fp32 baseline.
// Shapes: B=4, T=10, Ci=1, Hd=64, H=W=32, S=1024, future=10.
#define SS 1024
#define HD 64

__device__ __forceinline__ float sigm(float x) { return 1.f / (1.f + __expf(-x)); }

// ---------------------------------------------------------------------------
// K1: cc = conv3x3(concat(x, h)) -> 4 gates fused -> c_new (in place), h_cur
// grid (2, 64, 4) block 256; each thread does 2 pixels (p0, p0+256).
// ---------------------------------------------------------------------------
__global__ __launch_bounds__(256) void k_conv_gates(
    const float* __restrict__ xsrc, int xbs,
    const float* __restrict__ h,
    const float* __restrict__ wconv, const float* __restrict__ bconv,
    float* __restrict__ c, float* __restrict__ hc)
{
  __shared__ float4 wl[585];  // [ci*9+k] -> (w_i, w_f, w_o, w_g) for this hd
  const int hd = blockIdx.y, b = blockIdx.z;
  for (int i = threadIdx.x; i < 585; i += 256) {
    wl[i] = make_float4(wconv[(hd      ) * 585 + i],
                        wconv[(hd +  64) * 585 + i],
                        wconv[(hd + 128) * 585 + i],
                        wconv[(hd + 192) * 585 + i]);
  }
  __syncthreads();
  const int p0 = blockIdx.x * 512 + threadIdx.x;
  const int x = p0 & 31;
  const int y0 = p0 >> 5;
  float a00 = bconv[hd], a01 = bconv[hd + 64], a02 = bconv[hd + 128], a03 = bconv[hd + 192];
  float a10 = a00, a11 = a01, a12 = a02, a13 = a03;
  for (int ci = 0; ci < 65; ++ci) {
    const float* ip = (ci == 0) ? (xsrc + b * xbs) : (h + (size_t)(b * HD + ci - 1) * SS);
#pragma unroll
    for (int ky = 0; ky < 3; ++ky) {
      const int iy0 = y0 + ky - 1;
      const int iy1 = iy0 + 8;
#pragma unroll
      for (int kx = 0; kx < 3; ++kx) {
        const int ix = x + kx - 1;
        const bool xok = (unsigned)ix < 32u;
        const float4 w = wl[ci * 9 + ky * 3 + kx];
        const float v0 = (xok && (unsigned)iy0 < 32u) ? ip[iy0 * 32 + ix] : 0.f;
        const float v1 = (xok && (unsigned)iy1 < 32u) ? ip[iy1 * 32 + ix] : 0.f;
        a00 += w.x * v0; a01 += w.y * v0; a02 += w.z * v0; a03 += w.w * v0;
        a10 += w.x * v1; a11 += w.y * v1; a12 += w.z * v1; a13 += w.w * v1;
      }
    }
  }
  const int base = (b * HD + hd) * SS;
  {
    const float cn = sigm(a01) * c[base + p0] + sigm(a00) * tanhf(a03);
    c[base + p0] = cn;
    hc[base + p0] = sigm(a02) * tanhf(cn);
  }
  {
    const int p1 = p0 + 256;
    const float cn = sigm(a11) * c[base + p1] + sigm(a10) * tanhf(a13);
    c[base + p1] = cn;
    hc[base + p1] = sigm(a12) * tanhf(cn);
  }
}

// ---------------------------------------------------------------------------
// K2a: all 1x1 convs (conv_h: 192 rows from h_cur, conv_m: 128 rows from m).
// co in [0,128): hqk; [128,192): hv; [192,256): mk; [256,320): mv.
// grid (4, 320, 4) block 256.
// ---------------------------------------------------------------------------
__global__ __launch_bounds__(256) void k_conv1x1(
    const float* __restrict__ hcc, const float* __restrict__ mm,
    const float* __restrict__ wh, const float* __restrict__ bh,
    const float* __restrict__ wm, const float* __restrict__ bm,
    float* __restrict__ hqk, float* __restrict__ hv,
    float* __restrict__ mkb, float* __restrict__ mvb)
{
  __shared__ float4 wl4[16];
  const int co = blockIdx.y, b = blockIdx.z;
  const float* src; const float* wrow; float bias; float* dst;
  if (co < 192) {
    src = hcc + (size_t)b * HD * SS; wrow = wh + co * 64; bias = bh[co];
    dst = (co < 128) ? hqk + (size_t)(b * 128 + co) * SS
                     : hv + (size_t)(b * 64 + co - 128) * SS;
  } else {
    const int cm = co - 192;
    src = mm + (size_t)b * HD * SS; wrow = wm + cm * 64; bias = bm[cm];
    dst = (cm < 64) ? mkb + (size_t)(b * 64 + cm) * SS
                    : mvb + (size_t)(b * 64 + cm - 64) * SS;
  }
  if (threadIdx.x < 16) wl4[threadIdx.x] = ((const float4*)wrow)[threadIdx.x];
  __syncthreads();
  const int pix = blockIdx.x * 256 + threadIdx.x;
  float acc = bias;
#pragma unroll
  for (int i = 0; i < 16; ++i) {
    const float4 w = wl4[i];
    acc += w.x * src[(4 * i + 0) * SS + pix] + w.y * src[(4 * i + 1) * SS + pix]
         + w.z * src[(4 * i + 2) * SS + pix] + w.w * src[(4 * i + 3) * SS + pix];
  }
  dst[pix] = acc;
}

// ---------------------------------------------------------------------------
// K2t: transpose hv,mv [b][64][S] -> [b][S][64] so attention PV reads coalesce.
// grid (16, 2, 4) block 256.
// ---------------------------------------------------------------------------
__global__ __launch_bounds__(256) void k_transpose2(
    const float* __restrict__ hv, const float* __restrict__ mv,
    float* __restrict__ hvT, float* __restrict__ mvT)
{
  __shared__ float t[64][65];
  const int b = blockIdx.z;
  const float* src = blockIdx.y ? mv : hv;
  float* dst = blockIdx.y ? mvT : hvT;
  const int p0 = blockIdx.x * 64;
  const int lane = threadIdx.x & 63, r4 = threadIdx.x >> 6;
#pragma unroll
  for (int i = 0; i < 16; ++i) {
    const int co = i * 4 + r4;
    t[co][lane] = src[(size_t)(b * 64 + co) * SS + p0 + lane];
  }
  __syncthreads();
#pragma unroll
  for (int i = 0; i < 16; ++i) {
    const int p = i * 4 + r4;
    dst[(size_t)(b * SS + p0 + p) * 64 + lane] = t[lane][p];
  }
}

// ---------------------------------------------------------------------------
// K3: fused attention for 8 queries/block. scores -> softmax -> PV.
// grid (128, 2, 4) block 256. blockIdx.y: 0 = Zh (hk,hv), 1 = Zm (mk,mv).
// Writes Zh into zc rows [0,64), Zm into rows [64,128).
// ---------------------------------------------------------------------------
__global__ __launch_bounds__(256) void k_attn(
    const float* __restrict__ hqk, const float* __restrict__ mkb,
    const float* __restrict__ hvT, const float* __restrict__ mvT,
    float* __restrict__ zc)
{
  __shared__ float qs[64][8];
  __shared__ float sc[8][SS];
  const int b = blockIdx.z, at = blockIdx.y;
  const int s0 = blockIdx.x * 8;
  const float* q  = hqk + (size_t)b * 128 * SS;                     // rows 0-63
  const float* k  = at ? (mkb + (size_t)b * 64 * SS)
                       : (hqk + (size_t)b * 128 * SS + 64 * SS);    // rows 64-127
  const float* vT = at ? (mvT + (size_t)b * SS * 64)
                       : (hvT + (size_t)b * SS * 64);
  for (int i = threadIdx.x; i < 512; i += 256) {
    const int cc = i >> 3, si = i & 7;
    qs[cc][si] = q[cc * SS + s0 + si] * 0.125f;   // 1/sqrt(64)
  }
  __syncthreads();
  // scores: each thread covers t = {0,256,512,768} + tid for all 8 queries
  float acc[4][8];
#pragma unroll
  for (int ch = 0; ch < 4; ++ch)
#pragma unroll
    for (int si = 0; si < 8; ++si) acc[ch][si] = 0.f;
  for (int cc = 0; cc < 64; ++cc) {
    const float4 qa = *(const float4*)&qs[cc][0];
    const float4 qb = *(const float4*)&qs[cc][4];
#pragma unroll
    for (int ch = 0; ch < 4; ++ch) {
      const float kv = k[cc * SS + ch * 256 + threadIdx.x];
      acc[ch][0] += qa.x * kv; acc[ch][1] += qa.y * kv;
      acc[ch][2] += qa.z * kv; acc[ch][3] += qa.w * kv;
      acc[ch][4] += qb.x * kv; acc[ch][5] += qb.y * kv;
      acc[ch][6] += qb.z * kv; acc[ch][7] += qb.w * kv;
    }
  }
#pragma unroll
  for (int ch = 0; ch < 4; ++ch)
#pragma unroll
    for (int si = 0; si < 8; ++si)
      sc[si][ch * 256 + threadIdx.x] = acc[ch][si];
  __syncthreads();
  // softmax per query row; wave w handles rows 2w, 2w+1
  const int wv = threadIdx.x >> 6, lane = threadIdx.x & 63;
#pragma unroll
  for (int rr = 0; rr < 2; ++rr) {
    const int r = wv * 2 + rr;
    float mx = -1e30f;
    for (int t = lane; t < SS; t += 64) mx = fmaxf(mx, sc[r][t]);
#pragma unroll
    for (int o = 32; o; o >>= 1) mx = fmaxf(mx, __shfl_xor(mx, o));
    float sum = 0.f;
    for (int t = lane; t < SS; t += 64) {
      const float e = __expf(sc[r][t] - mx);
      sc[r][t] = e; sum += e;
    }
#pragma unroll
    for (int o = 32; o; o >>= 1) sum += __shfl_xor(sum, o);
    const float inv = 1.f / sum;
    for (int t = lane; t < SS; t += 64) sc[r][t] *= inv;
  }
  __syncthreads();
  // PV: thread -> (si = tid>>5, channel pair cp = tid&31)
  const int si = threadIdx.x >> 5;
  const int cp = threadIdx.x & 31;
  const float2* v2 = (const float2*)vT;
  float z0 = 0.f, z1 = 0.f;
  for (int t = 0; t < SS; t += 4) {
    const float4 a4 = *(const float4*)&sc[si][t];
    const float2 va = v2[(t + 0) * 32 + cp]; z0 += a4.x * va.x; z1 += a4.x * va.y;
    const float2 vb = v2[(t + 1) * 32 + cp]; z0 += a4.y * vb.x; z1 += a4.y * vb.y;
    const float2 vc = v2[(t + 2) * 32 + cp]; z0 += a4.z * vc.x; z1 += a4.z * vc.y;
    const float2 vd = v2[(t + 3) * 32 + cp]; z0 += a4.w * vd.x; z1 += a4.w * vd.y;
  }
  const int co = at * 64 + cp * 2;
  zc[(size_t)(b * 128 + co) * SS + s0 + si]     = z0;
  zc[(size_t)(b * 128 + co + 1) * SS + s0 + si] = z1;
}

// ---------------------------------------------------------------------------
// K4: Z = conv1x1(concat(Zh,Zm)) 128->64.  grid (4, 64, 4) block 256.
// ---------------------------------------------------------------------------
__global__ __launch_bounds__(256) void k_conv_z(
    const float* __restrict__ zc, const float* __restrict__ wz,
    const float* __restrict__ bz, float* __restrict__ Zb)
{
  __shared__ float4 wl4[32];
  const int co = blockIdx.y, b = blockIdx.z;
  if (threadIdx.x < 32) wl4[threadIdx.x] = ((const float4*)(wz + co * 128))[threadIdx.x];
  __syncthreads();
  const int pix = blockIdx.x * 256 + threadIdx.x;
  const float* src = zc + (size_t)b * 128 * SS;
  float acc = bz[co];
#pragma unroll
  for (int i = 0; i < 32; ++i) {
    const float4 w = wl4[i];
    acc += w.x * src[(4 * i + 0) * SS + pix] + w.y * src[(4 * i + 1) * SS + pix]
         + w.z * src[(4 * i + 2) * SS + pix] + w.w * src[(4 * i + 3) * SS + pix];
  }
  Zb[(size_t)(b * 64 + co) * SS + pix] = acc;
}

// ---------------------------------------------------------------------------
// K5: i2,g2,o2 = conv3x3(concat(Z, h_cur)) 128->192 fused with m,h update.
// grid (2, 64, 4) block 256; 2 pixels/thread.
// ---------------------------------------------------------------------------
__global__ __launch_bounds__(256) void k_conv_sa(
    const float* __restrict__ Zb, const float* __restrict__ hcc,
    const float* __restrict__ wsa, const float* __restrict__ bsa,
    float* __restrict__ m, float* __restrict__ h)
{
  __shared__ float4 wl[1152];  // [ci*9+k] -> (w_i2, w_g2, w_o2, 0)
  const int hd = blockIdx.y, b = blockIdx.z;
  for (int i = threadIdx.x; i < 1152; i += 256) {
    wl[i] = make_float4(wsa[(hd      ) * 1152 + i],
                        wsa[(hd +  64) * 1152 + i],
                        wsa[(hd + 128) * 1152 + i],
                        0.f);
  }
  __syncthreads();
  const int p0 = blockIdx.x * 512 + threadIdx.x;
  const int x = p0 & 31;
  const int y0 = p0 >> 5;
  float a00 = bsa[hd], a01 = bsa[hd + 64], a02 = bsa[hd + 128];
  float a10 = a00, a11 = a01, a12 = a02;
  for (int ci = 0; ci < 128; ++ci) {
    const float* ip = (ci < 64) ? (Zb + (size_t)(b * 64 + ci) * SS)
                                : (hcc + (size_t)(b * 64 + ci - 64) * SS);
#pragma unroll
    for (int ky = 0; ky < 3; ++ky) {
      const int iy0 = y0 + ky - 1;
      const int iy1 = iy0 + 8;
#pragma unroll
      for (int kx = 0; kx < 3; ++kx) {
        const int ix = x + kx - 1;
        const bool xok = (unsigned)ix < 32u;
        const float4 w = wl[ci * 9 + ky * 3 + kx];
        const float v0 = (xok && (unsigned)iy0 < 32u) ? ip[iy0 * 32 + ix] : 0.f;
        const float v1 = (xok && (unsigned)iy1 < 32u) ? ip[iy1 * 32 + ix] : 0.f;
        a00 += w.x * v0; a01 += w.y * v0; a02 += w.z * v0;
        a10 += w.x * v1; a11 += w.y * v1; a12 += w.z * v1;
      }
    }
  }
  const int base = (b * HD + hd) * SS;
  {
    const float i2 = sigm(a00);
    const float mn = i2 * tanhf(a01) + (1.f - i2) * m[base + p0];
    m[base + p0] = mn;
    h[base + p0] = sigm(a02) * mn;
  }
  {
    const int p1 = p0 + 256;
    const float i2 = sigm(a10);
    const float mn = i2 * tanhf(a11) + (1.f - i2) * m[base + p1];
    m[base + p1] = mn;
    h[base + p1] = sigm(a12) * mn;
  }
}

// ---------------------------------------------------------------------------
// K6: conv_out 64->1 (+optional sigmoid), writes next decoder input and output.
// grid (4, 4) block 256.
// ---------------------------------------------------------------------------
__global__ __launch_bounds__(256) void k_conv_out(
    const float* __restrict__ h, const float* __restrict__ wco,
    const float* __restrict__ bco,
    float* __restrict__ inp, float* __restrict__ out, int dosig, int j)
{
  __shared__ float4 wl4[16];
  if (threadIdx.x < 16) wl4[threadIdx.x] = ((const float4*)wco)[threadIdx.x];
  __syncthreads();
  const int b = blockIdx.y;
  const int pix = blockIdx.x * 256 + threadIdx.x;
  const float* src = h + (size_t)b * HD * SS;
  float acc = bco[0];
#pragma unroll
  for (int i = 0; i < 16; ++i) {
    const float4 w = wl4[i];
    acc += w.x * src[(4 * i + 0) * SS + pix] + w.y * src[(4 * i + 1) * SS + pix]
         + w.z * src[(4 * i + 2) * SS + pix] + w.w * src[(4 * i + 3) * SS + pix];
  }
  if (dosig) {
    acc = sigm(acc);
    out[(size_t)(b * 10 + j) * SS + pix] = acc;
  }
  inp[b * SS + pix] = acc;
}

// ---------------------------------------------------------------------------
extern "C" void kernel_launch(void* const* d_in, const int* in_sizes, int n_in,
                              void* d_out, int out_size, void* d_ws, size_t ws_size,
                              hipStream_t stream) {
  const float* x      = (const float*)d_in[0];
  const float* w_conv = (const float*)d_in[1];
  const float* b_conv = (const float*)d_in[2];
  const float* w_h    = (const float*)d_in[3];
  const float* b_h    = (const float*)d_in[4];
  const float* w_m    = (const float*)d_in[5];
  const float* b_m    = (const float*)d_in[6];
  const float* w_z    = (const float*)d_in[7];
  const float* b_z    = (const float*)d_in[8];
  const float* w_sa   = (const float*)d_in[9];
  const float* b_sa   = (const float*)d_in[10];
  const float* w_co   = (const float*)d_in[11];
  const float* b_co   = (const float*)d_in[12];
  float* out = (float*)d_out;

  float* ws  = (float*)d_ws;
  float* h   = ws;                 // [4][64][1024]
  float* c   = ws + 262144;
  float* m   = ws + 524288;
  float* hc  = ws + 786432;        // h_cur
  float* hqk = ws + 1048576;       // [4][128][1024] rows 0-63 q, 64-127 k
  float* hv  = ws + 1572864;       // [4][64][1024]
  float* mkb = ws + 1835008;
  float* mvb = ws + 2097152;
  float* hvT = ws + 2359296;       // [4][1024][64]
  float* mvT = ws + 2621440;
  float* zc  = ws + 2883584;       // [4][128][1024] (Zh | Zm)
  float* Zb  = ws + 3407872;       // [4][64][1024]
  float* inp = ws + 3670016;       // [4][1024]

  // zero initial h, c, m (contiguous)
  hipMemsetAsync(d_ws, 0, (size_t)3 * 262144 * sizeof(float), stream);

  auto cell = [&](const float* xsrc, int xbs) {
    k_conv_gates<<<dim3(2, 64, 4), 256, 0, stream>>>(xsrc, xbs, h, w_conv, b_conv, c, hc);
    k_conv1x1<<<dim3(4, 320, 4), 256, 0, stream>>>(hc, m, w_h, b_h, w_m, b_m, hqk, hv, mkb, mvb);
    k_transpose2<<<dim3(16, 2, 4), 256, 0, stream>>>(hv, mvb, hvT, mvT);
    k_attn<<<dim3(128, 2, 4), 256, 0, stream>>>(hqk, mkb, hvT, mvT, zc);
    k_conv_z<<<dim3(4, 64, 4), 256, 0, stream>>>(zc, w_z, b_z, Zb);
    k_conv_sa<<<dim3(2, 64, 4), 256, 0, stream>>>(Zb, hc, w_sa, b_sa, m, h);
  };

  // encoder: x[b][t] plane at (b*10+t)*1024
  for (int t = 0; t < 10; ++t) cell(x + (size_t)t * SS, 10 * SS);

  // first decoder input: conv_out(h) WITHOUT sigmoid
  k_conv_out<<<dim3(4, 4), 256, 0, stream>>>(h, w_co, b_co, inp, out, 0, 0);

  // decoder
  for (int j = 0; j < 10; ++j) {
    cell(inp, SS);
    k_conv_out<<<dim3(4, 4), 256, 0, stream>>>(h, w_co, b_co, inp, out, 1, j);
  }
}

// Round 5
// 4327.322 us; speedup vs baseline: 1.5078x; 1.5078x over previous
//
#include <hip/hip_runtime.h>
#include <math.h>

// SAConvLSTM: fp32 convs + bf16 MFMA flash-attention.
// Shapes: B=4, T=10, Ci=1, Hd=64, H=W=32, S=1024, future=10.
#define SS 1024
#define HD 64

typedef unsigned short u16;
typedef __attribute__((ext_vector_type(8))) __bf16 bf16x8;
typedef __attribute__((ext_vector_type(4))) float f32x4;

__device__ __forceinline__ float sigm(float x) { return 1.f / (1.f + __expf(-x)); }
__device__ __forceinline__ u16 f2b(float x) {
  return __builtin_bit_cast(unsigned short, (__bf16)x);
}
__device__ __forceinline__ float b2f(u16 u) {
  return (float)__builtin_bit_cast(__bf16, u);
}

// ---------------------------------------------------------------------------
// K1: cc = conv3x3(concat(x, h)) -> 4 gates fused -> c_new (in place), h_cur
// grid (2, 64, 4) block 256; each thread does 2 pixels (p0, p0+256).
// ---------------------------------------------------------------------------
__global__ __launch_bounds__(256) void k_conv_gates(
    const float* __restrict__ xsrc, int xbs,
    const float* __restrict__ h,
    const float* __restrict__ wconv, const float* __restrict__ bconv,
    float* __restrict__ c, float* __restrict__ hc)
{
  __shared__ float4 wl[585];  // [ci*9+k] -> (w_i, w_f, w_o, w_g) for this hd
  const int hd = blockIdx.y, b = blockIdx.z;
  for (int i = threadIdx.x; i < 585; i += 256) {
    wl[i] = make_float4(wconv[(hd      ) * 585 + i],
                        wconv[(hd +  64) * 585 + i],
                        wconv[(hd + 128) * 585 + i],
                        wconv[(hd + 192) * 585 + i]);
  }
  __syncthreads();
  const int p0 = blockIdx.x * 512 + threadIdx.x;
  const int x = p0 & 31;
  const int y0 = p0 >> 5;
  float a00 = bconv[hd], a01 = bconv[hd + 64], a02 = bconv[hd + 128], a03 = bconv[hd + 192];
  float a10 = a00, a11 = a01, a12 = a02, a13 = a03;
  for (int ci = 0; ci < 65; ++ci) {
    const float* ip = (ci == 0) ? (xsrc + b * xbs) : (h + (size_t)(b * HD + ci - 1) * SS);
#pragma unroll
    for (int ky = 0; ky < 3; ++ky) {
      const int iy0 = y0 + ky - 1;
      const int iy1 = iy0 + 8;
#pragma unroll
      for (int kx = 0; kx < 3; ++kx) {
        const int ix = x + kx - 1;
        const bool xok = (unsigned)ix < 32u;
        const float4 w = wl[ci * 9 + ky * 3 + kx];
        const float v0 = (xok && (unsigned)iy0 < 32u) ? ip[iy0 * 32 + ix] : 0.f;
        const float v1 = (xok && (unsigned)iy1 < 32u) ? ip[iy1 * 32 + ix] : 0.f;
        a00 += w.x * v0; a01 += w.y * v0; a02 += w.z * v0; a03 += w.w * v0;
        a10 += w.x * v1; a11 += w.y * v1; a12 += w.z * v1; a13 += w.w * v1;
      }
    }
  }
  const int base = (b * HD + hd) * SS;
  {
    const float cn = sigm(a01) * c[base + p0] + sigm(a00) * tanhf(a03);
    c[base + p0] = cn;
    hc[base + p0] = sigm(a02) * tanhf(cn);
  }
  {
    const int p1 = p0 + 256;
    const float cn = sigm(a11) * c[base + p1] + sigm(a10) * tanhf(a13);
    c[base + p1] = cn;
    hc[base + p1] = sigm(a12) * tanhf(cn);
  }
}

// ---------------------------------------------------------------------------
// K2a: all 1x1 convs -> bf16 outputs (channel-major [c][s]).
// co in [0,64): q; [64,128): k; [128,192): v; [192,256): mk; [256,320): mv.
// grid (4, 320, 4) block 256.
// ---------------------------------------------------------------------------
__global__ __launch_bounds__(256) void k_conv1x1(
    const float* __restrict__ hcc, const float* __restrict__ mm,
    const float* __restrict__ wh, const float* __restrict__ bh,
    const float* __restrict__ wm, const float* __restrict__ bm,
    u16* __restrict__ qn, u16* __restrict__ kn, u16* __restrict__ vh,
    u16* __restrict__ mkn, u16* __restrict__ mvn)
{
  __shared__ float4 wl4[16];
  const int co = blockIdx.y, b = blockIdx.z;
  const float* src; const float* wrow; float bias; u16* dst;
  if (co < 192) {
    src = hcc + (size_t)b * HD * SS; wrow = wh + co * 64; bias = bh[co];
    dst = (co < 64)  ? qn + (size_t)(b * 64 + co) * SS
        : (co < 128) ? kn + (size_t)(b * 64 + co - 64) * SS
                     : vh + (size_t)(b * 64 + co - 128) * SS;
  } else {
    const int cm = co - 192;
    src = mm + (size_t)b * HD * SS; wrow = wm + cm * 64; bias = bm[cm];
    dst = (cm < 64) ? mkn + (size_t)(b * 64 + cm) * SS
                    : mvn + (size_t)(b * 64 + cm - 64) * SS;
  }
  if (threadIdx.x < 16) wl4[threadIdx.x] = ((const float4*)wrow)[threadIdx.x];
  __syncthreads();
  const int pix = blockIdx.x * 256 + threadIdx.x;
  float acc = bias;
#pragma unroll
  for (int i = 0; i < 16; ++i) {
    const float4 w = wl4[i];
    acc += w.x * src[(4 * i + 0) * SS + pix] + w.y * src[(4 * i + 1) * SS + pix]
         + w.z * src[(4 * i + 2) * SS + pix] + w.w * src[(4 * i + 3) * SS + pix];
  }
  dst[pix] = f2b(acc);
}

// ---------------------------------------------------------------------------
// K2t: bf16 transpose [b][64][S] -> [b][S][64] for q (scaled 1/8), k, mk.
// grid (16, 3, 4) block 256.
// ---------------------------------------------------------------------------
__global__ __launch_bounds__(256) void k_transpose3(
    const u16* __restrict__ qn, const u16* __restrict__ kn,
    const u16* __restrict__ mkn,
    u16* __restrict__ qt, u16* __restrict__ kth, u16* __restrict__ ktm)
{
  __shared__ u16 t[64][68];
  const int b = blockIdx.z, which = blockIdx.y;
  const u16* src = (which == 0 ? qn : which == 1 ? kn : mkn) + (size_t)b * 64 * SS;
  u16* dst = (which == 0 ? qt : which == 1 ? kth : ktm) + (size_t)b * SS * 64;
  const int p0 = blockIdx.x * 64;
  const int lane = threadIdx.x & 63, r4 = threadIdx.x >> 6;
#pragma unroll
  for (int i = 0; i < 16; ++i) {
    const int co = i * 4 + r4;
    t[co][lane] = src[(size_t)co * SS + p0 + lane];
  }
  __syncthreads();
#pragma unroll
  for (int i = 0; i < 16; ++i) {
    const int p = i * 4 + r4;
    u16 u = t[lane][p];
    if (which == 0) u = f2b(b2f(u) * 0.125f);  // fold 1/sqrt(64); exact in bf16
    dst[(size_t)(p0 + p) * 64 + lane] = u;
  }
}

// ---------------------------------------------------------------------------
// K3: MFMA flash attention. grid (16, 2, 4) block 256 (4 waves).
// Block: 64-query tile; wave: 16 queries. KV steps of 64.
// ST[t][q] = mfma(A=K^T rows, B=Q rows); online softmax in-register
// (col=q=lane&15); P -> bf16 LDS; O^T[c][q] = mfma(A=V[c][t], B=P^T).
// Writes zc fp32: Zh rows [0,64), Zm rows [64,128).
// ---------------------------------------------------------------------------
__global__ __launch_bounds__(256) void k_attn_mfma(
    const u16* __restrict__ qt, const u16* __restrict__ kth,
    const u16* __restrict__ ktm, const u16* __restrict__ vh,
    const u16* __restrict__ mvn, float* __restrict__ zc)
{
  __shared__ u16 ldsK[4096];      // 64 t x 64 c, XOR-swizzled
  __shared__ u16 ldsV[4096];      // 64 c x 64 t, XOR-swizzled
  __shared__ u16 ldsP[4608];      // 4 waves x [16 q][72] (stride 72 kills conflicts)
  const int tid = threadIdx.x;
  const int wid = tid >> 6, lane = tid & 63, g = lane >> 4, n = lane & 15;
  const int b = blockIdx.z, at = blockIdx.y, q0 = blockIdx.x * 64;
  const u16* qtp = qt + (size_t)b * SS * 64;
  const u16* ktp = (at ? ktm : kth) + (size_t)b * SS * 64;
  const u16* vp  = (at ? mvn : vh) + (size_t)b * 64 * SS;
  const int q = q0 + wid * 16 + n;
  // Q B-fragments (col n=q, k=c contiguous-8 per group): hoisted, constant over KV.
  const bf16x8 bq0 = *(const bf16x8*)(qtp + (size_t)q * 64 + 8 * g);
  const bf16x8 bq1 = *(const bf16x8*)(qtp + (size_t)q * 64 + 32 + 8 * g);
  const f32x4 fzero = {0.f, 0.f, 0.f, 0.f};
  f32x4 o[4];
#pragma unroll
  for (int ct = 0; ct < 4; ++ct) o[ct] = fzero;
  float mrun = -1e30f, lrun = 0.f;
  u16* pb = ldsP + wid * 1152 + n * 72;

  for (int step = 0; step < 16; ++step) {
    const int t0 = step * 64;
    __syncthreads();
    // stage K^T tile (contiguous 8KB) and V tile (64 rows x 128B), swizzled
    const uint4* ks = (const uint4*)(ktp + (size_t)t0 * 64);
#pragma unroll
    for (int it = 0; it < 2; ++it) {
      const int i = tid + it * 256;
      const int sw = (i * 16) ^ ((i & 0x38) << 1);   // byte ^= ((row&7)<<4)
      *(uint4*)((char*)ldsK + sw) = ks[i];
      *(uint4*)((char*)ldsV + sw) =
          *(const uint4*)(vp + (size_t)(i >> 3) * SS + t0 + (i & 7) * 8);
    }
    __syncthreads();
    // ST = K^T x Q  (4 t-tiles x 2 c-chunks)
    f32x4 st[4];
#pragma unroll
    for (int tt = 0; tt < 4; ++tt) {
      const int row = tt * 16 + n;
      const int swz = (row & 7) << 4;
      const bf16x8 a0 = *(const bf16x8*)((char*)ldsK + ((row * 128 + g * 16) ^ swz));
      const bf16x8 a1 = *(const bf16x8*)((char*)ldsK + ((row * 128 + 64 + g * 16) ^ swz));
      f32x4 acc = fzero;
      acc = __builtin_amdgcn_mfma_f32_16x16x32_bf16(a0, bq0, acc, 0, 0, 0);
      acc = __builtin_amdgcn_mfma_f32_16x16x32_bf16(a1, bq1, acc, 0, 0, 0);
      st[tt] = acc;
    }
    // online softmax over this 64-key tile (per q = lane&15)
    float mt = -1e30f;
#pragma unroll
    for (int tt = 0; tt < 4; ++tt)
#pragma unroll
      for (int r = 0; r < 4; ++r) mt = fmaxf(mt, st[tt][r]);
    mt = fmaxf(mt, __shfl_xor(mt, 16));
    mt = fmaxf(mt, __shfl_xor(mt, 32));
    const float mnew = fmaxf(mrun, mt);
    const float f = __expf(mrun - mnew);
    float ps = 0.f;
#pragma unroll
    for (int tt = 0; tt < 4; ++tt) {
      const float p0e = __expf(st[tt][0] - mnew), p1e = __expf(st[tt][1] - mnew);
      const float p2e = __expf(st[tt][2] - mnew), p3e = __expf(st[tt][3] - mnew);
      ps += (p0e + p1e) + (p2e + p3e);
      const unsigned w0 = (unsigned)f2b(p0e) | ((unsigned)f2b(p1e) << 16);
      const unsigned w1 = (unsigned)f2b(p2e) | ((unsigned)f2b(p3e) << 16);
      *(unsigned*)(pb + tt * 16 + g * 4)     = w0;   // P[q][t], t = tt*16+4g+{0,1}
      *(unsigned*)(pb + tt * 16 + g * 4 + 2) = w1;   //            t = tt*16+4g+{2,3}
    }
    ps += __shfl_xor(ps, 16);
    ps += __shfl_xor(ps, 32);
    lrun = lrun * f + ps;
    mrun = mnew;
#pragma unroll
    for (int ct = 0; ct < 4; ++ct) {
      o[ct][0] *= f; o[ct][1] *= f; o[ct][2] *= f; o[ct][3] *= f;
    }
    // PV: O^T += V x P^T   (B-frags from own wave's P row; lgkmcnt orders LDS)
    const bf16x8 pb0 = *(const bf16x8*)(pb + 8 * g);
    const bf16x8 pb1 = *(const bf16x8*)(pb + 32 + 8 * g);
#pragma unroll
    for (int ct = 0; ct < 4; ++ct) {
      const int row = ct * 16 + n;
      const int swz = (row & 7) << 4;
      const bf16x8 v0 = *(const bf16x8*)((char*)ldsV + ((row * 128 + g * 16) ^ swz));
      const bf16x8 v1 = *(const bf16x8*)((char*)ldsV + ((row * 128 + 64 + g * 16) ^ swz));
      o[ct] = __builtin_amdgcn_mfma_f32_16x16x32_bf16(v0, pb0, o[ct], 0, 0, 0);
      o[ct] = __builtin_amdgcn_mfma_f32_16x16x32_bf16(v1, pb1, o[ct], 0, 0, 0);
    }
  }
  const float inv = 1.f / lrun;
  float* zp = zc + ((size_t)(b * 128 + at * 64)) * SS + q0 + wid * 16 + n;
#pragma unroll
  for (int ct = 0; ct < 4; ++ct)
#pragma unroll
    for (int r = 0; r < 4; ++r)
      zp[(size_t)(ct * 16 + g * 4 + r) * SS] = o[ct][r] * inv;
}

// ---------------------------------------------------------------------------
// K4: Z = conv1x1(concat(Zh,Zm)) 128->64.  grid (4, 64, 4) block 256.
// ---------------------------------------------------------------------------
__global__ __launch_bounds__(256) void k_conv_z(
    const float* __restrict__ zc, const float* __restrict__ wz,
    const float* __restrict__ bz, float* __restrict__ Zb)
{
  __shared__ float4 wl4[32];
  const int co = blockIdx.y, b = blockIdx.z;
  if (threadIdx.x < 32) wl4[threadIdx.x] = ((const float4*)(wz + co * 128))[threadIdx.x];
  __syncthreads();
  const int pix = blockIdx.x * 256 + threadIdx.x;
  const float* src = zc + (size_t)b * 128 * SS;
  float acc = bz[co];
#pragma unroll
  for (int i = 0; i < 32; ++i) {
    const float4 w = wl4[i];
    acc += w.x * src[(4 * i + 0) * SS + pix] + w.y * src[(4 * i + 1) * SS + pix]
         + w.z * src[(4 * i + 2) * SS + pix] + w.w * src[(4 * i + 3) * SS + pix];
  }
  Zb[(size_t)(b * 64 + co) * SS + pix] = acc;
}

// ---------------------------------------------------------------------------
// K5: i2,g2,o2 = conv3x3(concat(Z, h_cur)) 128->192 fused with m,h update.
// grid (2, 64, 4) block 256; 2 pixels/thread.
// ---------------------------------------------------------------------------
__global__ __launch_bounds__(256) void k_conv_sa(
    const float* __restrict__ Zb, const float* __restrict__ hcc,
    const float* __restrict__ wsa, const float* __restrict__ bsa,
    float* __restrict__ m, float* __restrict__ h)
{
  __shared__ float4 wl[1152];  // [ci*9+k] -> (w_i2, w_g2, w_o2, 0)
  const int hd = blockIdx.y, b = blockIdx.z;
  for (int i = threadIdx.x; i < 1152; i += 256) {
    wl[i] = make_float4(wsa[(hd      ) * 1152 + i],
                        wsa[(hd +  64) * 1152 + i],
                        wsa[(hd + 128) * 1152 + i],
                        0.f);
  }
  __syncthreads();
  const int p0 = blockIdx.x * 512 + threadIdx.x;
  const int x = p0 & 31;
  const int y0 = p0 >> 5;
  float a00 = bsa[hd], a01 = bsa[hd + 64], a02 = bsa[hd + 128];
  float a10 = a00, a11 = a01, a12 = a02;
  for (int ci = 0; ci < 128; ++ci) {
    const float* ip = (ci < 64) ? (Zb + (size_t)(b * 64 + ci) * SS)
                                : (hcc + (size_t)(b * 64 + ci - 64) * SS);
#pragma unroll
    for (int ky = 0; ky < 3; ++ky) {
      const int iy0 = y0 + ky - 1;
      const int iy1 = iy0 + 8;
#pragma unroll
      for (int kx = 0; kx < 3; ++kx) {
        const int ix = x + kx - 1;
        const bool xok = (unsigned)ix < 32u;
        const float4 w = wl[ci * 9 + ky * 3 + kx];
        const float v0 = (xok && (unsigned)iy0 < 32u) ? ip[iy0 * 32 + ix] : 0.f;
        const float v1 = (xok && (unsigned)iy1 < 32u) ? ip[iy1 * 32 + ix] : 0.f;
        a00 += w.x * v0; a01 += w.y * v0; a02 += w.z * v0;
        a10 += w.x * v1; a11 += w.y * v1; a12 += w.z * v1;
      }
    }
  }
  const int base = (b * HD + hd) * SS;
  {
    const float i2 = sigm(a00);
    const float mn = i2 * tanhf(a01) + (1.f - i2) * m[base + p0];
    m[base + p0] = mn;
    h[base + p0] = sigm(a02) * mn;
  }
  {
    const int p1 = p0 + 256;
    const float i2 = sigm(a10);
    const float mn = i2 * tanhf(a11) + (1.f - i2) * m[base + p1];
    m[base + p1] = mn;
    h[base + p1] = sigm(a12) * mn;
  }
}

// ---------------------------------------------------------------------------
// K6: conv_out 64->1 (+optional sigmoid), writes next decoder input and output.
// grid (4, 4) block 256.
// ---------------------------------------------------------------------------
__global__ __launch_bounds__(256) void k_conv_out(
    const float* __restrict__ h, const float* __restrict__ wco,
    const float* __restrict__ bco,
    float* __restrict__ inp, float* __restrict__ out, int dosig, int j)
{
  __shared__ float4 wl4[16];
  if (threadIdx.x < 16) wl4[threadIdx.x] = ((const float4*)wco)[threadIdx.x];
  __syncthreads();
  const int b = blockIdx.y;
  const int pix = blockIdx.x * 256 + threadIdx.x;
  const float* src = h + (size_t)b * HD * SS;
  float acc = bco[0];
#pragma unroll
  for (int i = 0; i < 16; ++i) {
    const float4 w = wl4[i];
    acc += w.x * src[(4 * i + 0) * SS + pix] + w.y * src[(4 * i + 1) * SS + pix]
         + w.z * src[(4 * i + 2) * SS + pix] + w.w * src[(4 * i + 3) * SS + pix];
  }
  if (dosig) {
    acc = sigm(acc);
    out[(size_t)(b * 10 + j) * SS + pix] = acc;
  }
  inp[b * SS + pix] = acc;
}

// ---------------------------------------------------------------------------
extern "C" void kernel_launch(void* const* d_in, const int* in_sizes, int n_in,
                              void* d_out, int out_size, void* d_ws, size_t ws_size,
                              hipStream_t stream) {
  const float* x      = (const float*)d_in[0];
  const float* w_conv = (const float*)d_in[1];
  const float* b_conv = (const float*)d_in[2];
  const float* w_h    = (const float*)d_in[3];
  const float* b_h    = (const float*)d_in[4];
  const float* w_m    = (const float*)d_in[5];
  const float* b_m    = (const float*)d_in[6];
  const float* w_z    = (const float*)d_in[7];
  const float* b_z    = (const float*)d_in[8];
  const float* w_sa   = (const float*)d_in[9];
  const float* b_sa   = (const float*)d_in[10];
  const float* w_co   = (const float*)d_in[11];
  const float* b_co   = (const float*)d_in[12];
  float* out = (float*)d_out;

  float* ws  = (float*)d_ws;
  float* h   = ws;                 // [4][64][1024] fp32
  float* c   = ws + 262144;
  float* m   = ws + 524288;
  float* hc  = ws + 786432;        // h_cur
  float* zc  = ws + 1048576;       // [4][128][1024] fp32 (Zh | Zm)
  float* Zb  = ws + 1572864;       // [4][64][1024] fp32
  float* inp = ws + 1835008;       // [4][1024]
  u16* ub  = (u16*)(ws + 1839104); // bf16 region
  u16* qn  = ub;                   // [4][64][1024] bf16, each 262144 u16
  u16* kn  = ub + 262144;
  u16* vh  = ub + 524288;
  u16* mkn = ub + 786432;
  u16* mvn = ub + 1048576;
  u16* qtb = ub + 1310720;         // [4][1024][64] bf16 (q^T, x0.125)
  u16* kth = ub + 1572864;         // [4][1024][64]
  u16* ktm = ub + 1835008;         // [4][1024][64]

  // zero initial h, c, m (contiguous)
  hipMemsetAsync(d_ws, 0, (size_t)3 * 262144 * sizeof(float), stream);

  auto cell = [&](const float* xsrc, int xbs) {
    k_conv_gates<<<dim3(2, 64, 4), 256, 0, stream>>>(xsrc, xbs, h, w_conv, b_conv, c, hc);
    k_conv1x1<<<dim3(4, 320, 4), 256, 0, stream>>>(hc, m, w_h, b_h, w_m, b_m,
                                                   qn, kn, vh, mkn, mvn);
    k_transpose3<<<dim3(16, 3, 4), 256, 0, stream>>>(qn, kn, mkn, qtb, kth, ktm);
    k_attn_mfma<<<dim3(16, 2, 4), 256, 0, stream>>>(qtb, kth, ktm, vh, mvn, zc);
    k_conv_z<<<dim3(4, 64, 4), 256, 0, stream>>>(zc, w_z, b_z, Zb);
    k_conv_sa<<<dim3(2, 64, 4), 256, 0, stream>>>(Zb, hc, w_sa, b_sa, m, h);
  };

  // encoder: x[b][t] plane at (b*10+t)*1024
  for (int t = 0; t < 10; ++t) cell(x + (size_t)t * SS, 10 * SS);

  // first decoder input: conv_out(h) WITHOUT sigmoid
  k_conv_out<<<dim3(4, 4), 256, 0, stream>>>(h, w_co, b_co, inp, out, 0, 0);

  // decoder
  for (int j = 0; j < 10; ++j) {
    cell(inp, SS);
    k_conv_out<<<dim3(4, 4), 256, 0, stream>>>(h, w_co, b_co, inp, out, 1, j);
  }
}

// Round 7
// 1995.402 us; speedup vs baseline: 3.2699x; 2.1686x over previous
//
#include <hip/hip_runtime.h>
#include <math.h>

// SAConvLSTM: all-MFMA implicit-GEMM convs + flash attention, pixel-major bf16.
// Shapes: B=4, T=10, Ci=1, Hd=64, H=W=32, S=1024, future=10.
#define SS 1024

typedef unsigned short u16;
typedef __attribute__((ext_vector_type(8))) __bf16 bf16x8;
typedef __attribute__((ext_vector_type(4))) float f32x4;

#define MFMA(a,b,c) __builtin_amdgcn_mfma_f32_16x16x32_bf16(a,b,c,0,0,0)

__device__ __forceinline__ float sigm(float x){ return 1.f/(1.f+__expf(-x)); }
__device__ __forceinline__ u16 f2b(float x){ return __builtin_bit_cast(u16,(__bf16)x); }
__device__ __forceinline__ float b2f(u16 u){ return (float)__builtin_bit_cast(__bf16,u); }
__device__ __forceinline__ bf16x8 ldb8(const u16* p){ return *(const bf16x8*)p; }
__device__ __forceinline__ void st4b(u16* p, const f32x4 v){
  union { u16 u[4]; uint2 w; } t;
  t.u[0]=f2b(v[0]); t.u[1]=f2b(v[1]); t.u[2]=f2b(v[2]); t.u[3]=f2b(v[3]);
  *(uint2*)p = t.w;
}

// ---------------------------------------------------------------------------
// Weight prepack (every launch; same work each call). bf16 A-tiles [step][co][32].
// Wg[19][256][32]: steps 0..17 = tap*2+half over h-channels; step 18 = x taps.
// Whm[2][320][32]: rows 0..191 w_h (q rows x0.125), 192..319 w_m.
// Wzp[4][64][32]; Wsap[36][192][32] (step = tap*4 + ci-quarter).
// ---------------------------------------------------------------------------
__global__ __launch_bounds__(256) void k_prep(
    const float* __restrict__ wconv, const float* __restrict__ wh,
    const float* __restrict__ wm, const float* __restrict__ wz,
    const float* __restrict__ wsa,
    u16* __restrict__ Wg, u16* __restrict__ Whm,
    u16* __restrict__ Wzp, u16* __restrict__ Wsap)
{
  const int idx = blockIdx.x*256 + threadIdx.x;
  if (idx < 155648) {                       // 19*256*32
    const int step = idx >> 13, co = (idx >> 5) & 255, j = idx & 31;
    float v = 0.f;
    if (step < 18) {
      const int tap = step >> 1, ci = 1 + (step & 1)*32 + j;
      v = wconv[co*585 + ci*9 + tap];
    } else if (j < 9) {
      v = wconv[co*585 + j];                // ci=0 (x), tap j
    }
    Wg[idx] = f2b(v);
    return;
  }
  int l = idx - 155648;
  if (l < 20480) {                          // 2*320*32
    const int step = l / 10240, row = (l >> 5) % 320, j = l & 31;
    const int ci = step*32 + j;
    const float v = (row < 192) ? wh[row*64+ci]*(row < 64 ? 0.125f : 1.f)
                                : wm[(row-192)*64+ci];
    Whm[l] = f2b(v);
    return;
  }
  l -= 20480;
  if (l < 8192) {                           // 4*64*32
    const int step = l >> 11, co = (l >> 5) & 63, j = l & 31;
    Wzp[l] = f2b(wz[co*128 + step*32 + j]);
    return;
  }
  l -= 8192;
  if (l < 221184) {                         // 36*192*32
    const int step = l / 6144, co = (l >> 5) % 192, j = l & 31;
    const int tap = step >> 2, ci = (step & 3)*32 + j;
    Wsap[l] = f2b(wsa[(co*128+ci)*9 + tap]);
  }
}

// ---------------------------------------------------------------------------
// K1: conv3x3(concat(x,h)) -> 4 gates (MFMA) -> c update (fp32), hc -> xcat.
// grid (16,4) block 256. Block: 64 s; wave: co-tiles {w,w+4,w+8,w+12} x 4 s-tiles.
// ---------------------------------------------------------------------------
__global__ __launch_bounds__(256) void k_gates(
    const u16* __restrict__ hTb, const float* __restrict__ xsrc, int xbs,
    const u16* __restrict__ Wg, const float* __restrict__ bconv,
    float* __restrict__ cT, u16* __restrict__ xcat)
{
  const int b = blockIdx.y, s0 = blockIdx.x*64;
  const int tid = threadIdx.x, wid = tid>>6, lane = tid&63, gl = lane>>4, n = lane&15;
  const u16* hb = hTb + (size_t)b*SS*64;
  f32x4 acc[4][4];
#pragma unroll
  for (int g4 = 0; g4 < 4; ++g4) {
    const int co = g4*64 + wid*16 + gl*4;
    const f32x4 bb = { bconv[co], bconv[co+1], bconv[co+2], bconv[co+3] };
#pragma unroll
    for (int st = 0; st < 4; ++st) acc[g4][st] = bb;
  }
  // x-patch B-fragment per s-tile (k = taps 0..8, padded to 32)
  bf16x8 xb[4];
#pragma unroll
  for (int st = 0; st < 4; ++st) {
    const int s = s0 + st*16 + n, y = s>>5, x = s&31;
    union { u16 u[8]; bf16x8 v; } t;
#pragma unroll
    for (int j = 0; j < 8; ++j) t.u[j] = 0;
    if (gl == 0) {
#pragma unroll
      for (int j = 0; j < 8; ++j) {
        const int dy = j/3 - 1, dx = j%3 - 1;
        if ((unsigned)(y+dy) < 32u && (unsigned)(x+dx) < 32u)
          t.u[j] = f2b(xsrc[b*xbs + s + dy*32 + dx]);
      }
    } else if (gl == 1) {   // k=8 -> tap 8 (dy=1,dx=1)
      if (y+1 < 32 && x+1 < 32) t.u[0] = f2b(xsrc[b*xbs + s + 33]);
    }
    xb[st] = t.v;
  }
#pragma unroll
  for (int step = 0; step < 18; ++step) {
    const int tap = step>>1, half = step&1;
    const int dy = tap/3 - 1, dx = tap%3 - 1;
    bf16x8 a[4];
#pragma unroll
    for (int g4 = 0; g4 < 4; ++g4)
      a[g4] = ldb8(Wg + step*8192 + (g4*64 + wid*16 + n)*32 + gl*8);
#pragma unroll
    for (int st = 0; st < 4; ++st) {
      const int s = s0 + st*16 + n, y = s>>5, x = s&31;
      bf16x8 bv = {};
      if ((unsigned)(y+dy) < 32u && (unsigned)(x+dx) < 32u)
        bv = ldb8(hb + (size_t)(s + dy*32 + dx)*64 + half*32 + gl*8);
#pragma unroll
      for (int g4 = 0; g4 < 4; ++g4) acc[g4][st] = MFMA(a[g4], bv, acc[g4][st]);
    }
  }
  {  // x step
    bf16x8 a[4];
#pragma unroll
    for (int g4 = 0; g4 < 4; ++g4)
      a[g4] = ldb8(Wg + 18*8192 + (g4*64 + wid*16 + n)*32 + gl*8);
#pragma unroll
    for (int st = 0; st < 4; ++st)
#pragma unroll
      for (int g4 = 0; g4 < 4; ++g4) acc[g4][st] = MFMA(a[g4], xb[st], acc[g4][st]);
  }
  const int hd0 = wid*16 + gl*4;
#pragma unroll
  for (int st = 0; st < 4; ++st) {
    const int s = s0 + st*16 + n;
    float* cp = cT + ((size_t)b*SS + s)*64 + hd0;
    f32x4 cv = *(f32x4*)cp, hcv;
#pragma unroll
    for (int rr = 0; rr < 4; ++rr) {
      const float cn = sigm(acc[1][st][rr])*cv[rr] + sigm(acc[0][st][rr])*tanhf(acc[3][st][rr]);
      cv[rr] = cn;
      hcv[rr] = sigm(acc[2][st][rr])*tanhf(cn);
    }
    *(f32x4*)cp = cv;
    st4b(xcat + ((size_t)b*SS + s)*128 + 64 + hd0, hcv);
  }
}

// ---------------------------------------------------------------------------
// K2: all 1x1 convs (q,k,v from hc; mk,mv from m). grid (16,4) block 256.
// Wave w: co-slices {q,k,v,mk,mv} x 16 rows each x 4 s-tiles. K=64 (2 steps).
// ---------------------------------------------------------------------------
__global__ __launch_bounds__(256) void k_1x1(
    const u16* __restrict__ xcat, const u16* __restrict__ mTb,
    const u16* __restrict__ Whm, const float* __restrict__ bh,
    const float* __restrict__ bm,
    u16* __restrict__ qT, u16* __restrict__ kT, u16* __restrict__ mkT,
    u16* __restrict__ vC, u16* __restrict__ mvC)
{
  const int b = blockIdx.y, s0 = blockIdx.x*64;
  const int tid = threadIdx.x, wid = tid>>6, lane = tid&63, gl = lane>>4, n = lane&15;
  const int r0 = wid*16, cb = r0 + gl*4;
  f32x4 acc[5][4];
  {
    const f32x4 bq = { bh[cb]*0.125f, bh[cb+1]*0.125f, bh[cb+2]*0.125f, bh[cb+3]*0.125f };
    const f32x4 bk = { bh[64+cb], bh[64+cb+1], bh[64+cb+2], bh[64+cb+3] };
    const f32x4 bv = { bh[128+cb], bh[128+cb+1], bh[128+cb+2], bh[128+cb+3] };
    const f32x4 bmk = { bm[cb], bm[cb+1], bm[cb+2], bm[cb+3] };
    const f32x4 bmv = { bm[64+cb], bm[64+cb+1], bm[64+cb+2], bm[64+cb+3] };
#pragma unroll
    for (int st = 0; st < 4; ++st) {
      acc[0][st]=bq; acc[1][st]=bk; acc[2][st]=bv; acc[3][st]=bmk; acc[4][st]=bmv;
    }
  }
#pragma unroll
  for (int step = 0; step < 2; ++step) {
    bf16x8 a[5];
#pragma unroll
    for (int tt = 0; tt < 5; ++tt)
      a[tt] = ldb8(Whm + step*10240 + (tt*64 + r0 + n)*32 + gl*8);
#pragma unroll
    for (int st = 0; st < 4; ++st) {
      const int s = s0 + st*16 + n;
      const bf16x8 bhc = ldb8(xcat + ((size_t)b*SS+s)*128 + 64 + step*32 + gl*8);
      const bf16x8 bmm = ldb8(mTb + ((size_t)b*SS+s)*64 + step*32 + gl*8);
      acc[0][st] = MFMA(a[0], bhc, acc[0][st]);
      acc[1][st] = MFMA(a[1], bhc, acc[1][st]);
      acc[2][st] = MFMA(a[2], bhc, acc[2][st]);
      acc[3][st] = MFMA(a[3], bmm, acc[3][st]);
      acc[4][st] = MFMA(a[4], bmm, acc[4][st]);
    }
  }
#pragma unroll
  for (int st = 0; st < 4; ++st) {
    const int s = s0 + st*16 + n;
    const size_t ps = ((size_t)b*SS + s)*64 + cb;
    st4b(qT + ps, acc[0][st]);
    st4b(kT + ps, acc[1][st]);
    st4b(mkT + ps, acc[3][st]);
#pragma unroll
    for (int rr = 0; rr < 4; ++rr) {
      vC[((size_t)b*64 + cb + rr)*SS + s] = f2b(acc[2][st][rr]);
      mvC[((size_t)b*64 + cb + rr)*SS + s] = f2b(acc[4][st][rr]);
    }
  }
}

// ---------------------------------------------------------------------------
// K3: MFMA flash attention, no K/V LDS, no barriers. grid (16,2,4) block 256.
// Wave: 16 queries. QK^T: A=kT rows t, B=qT (D col=q=n). PV: A=P(ldsP), B=vC
// (D row=q, col=c) -> zT [s][128] pixel-major (Zh cols 0..63, Zm 64..127).
// ---------------------------------------------------------------------------
__global__ __launch_bounds__(256) void k_attn2(
    const u16* __restrict__ qT, const u16* __restrict__ kT,
    const u16* __restrict__ mkT, const u16* __restrict__ vC,
    const u16* __restrict__ mvC, u16* __restrict__ zT)
{
  __shared__ u16 ldsP[4*16*72];
  const int tid = threadIdx.x, wid = tid>>6, lane = tid&63, gl = lane>>4, n = lane&15;
  const int b = blockIdx.z, at = blockIdx.y, q0 = blockIdx.x*64 + wid*16;
  const u16* qb = qT + (size_t)b*SS*64;
  const u16* kb = (at ? mkT : kT) + (size_t)b*SS*64;
  const u16* vb = (at ? mvC : vC) + (size_t)b*64*SS;
  const bf16x8 bq0 = ldb8(qb + (size_t)(q0+n)*64 + gl*8);
  const bf16x8 bq1 = ldb8(qb + (size_t)(q0+n)*64 + 32 + gl*8);
  f32x4 o[4];
#pragma unroll
  for (int ct = 0; ct < 4; ++ct) o[ct] = (f32x4){0.f,0.f,0.f,0.f};
  float mrun = -1e30f, lrun = 0.f;
  u16* pb = ldsP + wid*1152 + n*72;

  for (int step = 0; step < 16; ++step) {
    const int t0 = step*64;
    f32x4 st4[4];
#pragma unroll
    for (int tt = 0; tt < 4; ++tt) {
      const u16* kr = kb + (size_t)(t0 + tt*16 + n)*64;
      f32x4 a = {0.f,0.f,0.f,0.f};
      a = MFMA(ldb8(kr + gl*8), bq0, a);
      a = MFMA(ldb8(kr + 32 + gl*8), bq1, a);
      st4[tt] = a;
    }
    float mt = -1e30f;
#pragma unroll
    for (int tt = 0; tt < 4; ++tt)
#pragma unroll
      for (int rr = 0; rr < 4; ++rr) mt = fmaxf(mt, st4[tt][rr]);
    mt = fmaxf(mt, __shfl_xor(mt, 16));
    mt = fmaxf(mt, __shfl_xor(mt, 32));
    const float mnew = fmaxf(mrun, mt);
    const float f = __expf(mrun - mnew);
    float ps = 0.f;
#pragma unroll
    for (int tt = 0; tt < 4; ++tt) {
      const float p0e = __expf(st4[tt][0]-mnew), p1e = __expf(st4[tt][1]-mnew);
      const float p2e = __expf(st4[tt][2]-mnew), p3e = __expf(st4[tt][3]-mnew);
      ps += (p0e + p1e) + (p2e + p3e);
      *(unsigned*)(pb + tt*16 + gl*4)     = (unsigned)f2b(p0e) | ((unsigned)f2b(p1e)<<16);
      *(unsigned*)(pb + tt*16 + gl*4 + 2) = (unsigned)f2b(p2e) | ((unsigned)f2b(p3e)<<16);
    }
    ps += __shfl_xor(ps, 16);
    ps += __shfl_xor(ps, 32);
    lrun = lrun*f + ps;
    mrun = mnew;
    // rescale O by the ROW-q factor (stats live on col-q lanes -> shuffle)
    float fr[4];
#pragma unroll
    for (int rr = 0; rr < 4; ++rr) fr[rr] = __shfl(f, gl*4 + rr);
#pragma unroll
    for (int ct = 0; ct < 4; ++ct)
#pragma unroll
      for (int rr = 0; rr < 4; ++rr) o[ct][rr] *= fr[rr];
    const bf16x8 pa0 = ldb8(pb + gl*8);
    const bf16x8 pa1 = ldb8(pb + 32 + gl*8);
#pragma unroll
    for (int ct = 0; ct < 4; ++ct) {
      const u16* vr = vb + (size_t)(ct*16 + n)*SS + t0;
      o[ct] = MFMA(pa0, ldb8(vr + gl*8), o[ct]);
      o[ct] = MFMA(pa1, ldb8(vr + 32 + gl*8), o[ct]);
    }
  }
  float invr[4];
#pragma unroll
  for (int rr = 0; rr < 4; ++rr) invr[rr] = 1.f / __shfl(lrun, gl*4 + rr);
#pragma unroll
  for (int ct = 0; ct < 4; ++ct)
#pragma unroll
    for (int rr = 0; rr < 4; ++rr)
      zT[((size_t)b*SS + q0 + gl*4 + rr)*128 + at*64 + ct*16 + n] = f2b(o[ct][rr]*invr[rr]);
}

// ---------------------------------------------------------------------------
// K4: conv_z 128->64 (K=4 steps) -> xcat cols 0..63. grid (16,4) block 256.
// ---------------------------------------------------------------------------
__global__ __launch_bounds__(256) void k_z(
    const u16* __restrict__ zT, const u16* __restrict__ Wzp,
    const float* __restrict__ bz, u16* __restrict__ xcat)
{
  const int b = blockIdx.y, s0 = blockIdx.x*64;
  const int tid = threadIdx.x, wid = tid>>6, lane = tid&63, gl = lane>>4, n = lane&15;
  const int s = s0 + wid*16 + n;
  f32x4 acc[4];
#pragma unroll
  for (int ct = 0; ct < 4; ++ct) {
    const int co = ct*16 + gl*4;
    acc[ct] = (f32x4){ bz[co], bz[co+1], bz[co+2], bz[co+3] };
  }
#pragma unroll
  for (int step = 0; step < 4; ++step) {
    const bf16x8 bv = ldb8(zT + ((size_t)b*SS + s)*128 + step*32 + gl*8);
#pragma unroll
    for (int ct = 0; ct < 4; ++ct) {
      const bf16x8 a = ldb8(Wzp + step*2048 + (ct*16 + n)*32 + gl*8);
      acc[ct] = MFMA(a, bv, acc[ct]);
    }
  }
#pragma unroll
  for (int ct = 0; ct < 4; ++ct)
    st4b(xcat + ((size_t)b*SS + s)*128 + ct*16 + gl*4, acc[ct]);
}

// ---------------------------------------------------------------------------
// K5: conv3x3(concat(Z,hc)) -> i2,g2,o2 (MFMA) -> m (fp32) and h updates.
// grid (16,4) block 256; wave: co-triples {w,w+4,w+8} x 4 s-tiles; 36 K-steps.
// ---------------------------------------------------------------------------
__global__ __launch_bounds__(256) void k_sa(
    const u16* __restrict__ xcat, const u16* __restrict__ Wsap,
    const float* __restrict__ bsa,
    float* __restrict__ mT, u16* __restrict__ mTb, u16* __restrict__ hTb)
{
  const int b = blockIdx.y, s0 = blockIdx.x*64;
  const int tid = threadIdx.x, wid = tid>>6, lane = tid&63, gl = lane>>4, n = lane&15;
  const int hd0 = wid*16 + gl*4;
  f32x4 acc[3][4];
#pragma unroll
  for (int i = 0; i < 3; ++i) {
    const int co = i*64 + hd0;
    const f32x4 bb = { bsa[co], bsa[co+1], bsa[co+2], bsa[co+3] };
#pragma unroll
    for (int st = 0; st < 4; ++st) acc[i][st] = bb;
  }
#pragma unroll
  for (int step = 0; step < 36; ++step) {
    const int tap = step>>2, qq = step&3;
    const int dy = tap/3 - 1, dx = tap%3 - 1;
    bf16x8 a[3];
#pragma unroll
    for (int i = 0; i < 3; ++i)
      a[i] = ldb8(Wsap + step*6144 + (i*64 + wid*16 + n)*32 + gl*8);
#pragma unroll
    for (int st = 0; st < 4; ++st) {
      const int s = s0 + st*16 + n, y = s>>5, x = s&31;
      bf16x8 bv = {};
      if ((unsigned)(y+dy) < 32u && (unsigned)(x+dx) < 32u)
        bv = ldb8(xcat + ((size_t)b*SS + s + dy*32 + dx)*128 + qq*32 + gl*8);
#pragma unroll
      for (int i = 0; i < 3; ++i) acc[i][st] = MFMA(a[i], bv, acc[i][st]);
    }
  }
#pragma unroll
  for (int st = 0; st < 4; ++st) {
    const int s = s0 + st*16 + n;
    float* mp = mT + ((size_t)b*SS + s)*64 + hd0;
    f32x4 mv4 = *(f32x4*)mp, hv;
#pragma unroll
    for (int rr = 0; rr < 4; ++rr) {
      const float i2 = sigm(acc[0][st][rr]);
      const float mn = i2*tanhf(acc[1][st][rr]) + (1.f - i2)*mv4[rr];
      mv4[rr] = mn;
      hv[rr] = sigm(acc[2][st][rr])*mn;
    }
    *(f32x4*)mp = mv4;
    st4b(mTb + ((size_t)b*SS + s)*64 + hd0, mv4);
    st4b(hTb + ((size_t)b*SS + s)*64 + hd0, hv);
  }
}

// ---------------------------------------------------------------------------
// K6: conv_out 64->1 (+optional sigmoid) from bf16 h. grid (4,4) block 256.
// ---------------------------------------------------------------------------
__global__ __launch_bounds__(256) void k_out2(
    const u16* __restrict__ hTb, const float* __restrict__ wco,
    const float* __restrict__ bco,
    float* __restrict__ inp, float* __restrict__ out, int dosig, int j)
{
  __shared__ float wsm[64];
  if (threadIdx.x < 64) wsm[threadIdx.x] = wco[threadIdx.x];
  __syncthreads();
  const int b = blockIdx.y;
  const int s = blockIdx.x*256 + threadIdx.x;
  const u16* hp = hTb + ((size_t)b*SS + s)*64;
  float acc = bco[0];
#pragma unroll
  for (int i = 0; i < 64; ++i) acc += b2f(hp[i]) * wsm[i];
  if (dosig) {
    acc = sigm(acc);
    out[((size_t)b*10 + j)*SS + s] = acc;
  }
  inp[b*SS + s] = acc;
}

// ---------------------------------------------------------------------------
extern "C" void kernel_launch(void* const* d_in, const int* in_sizes, int n_in,
                              void* d_out, int out_size, void* d_ws, size_t ws_size,
                              hipStream_t stream) {
  const float* x      = (const float*)d_in[0];
  const float* w_conv = (const float*)d_in[1];
  const float* b_conv = (const float*)d_in[2];
  const float* w_h    = (const float*)d_in[3];
  const float* b_h    = (const float*)d_in[4];
  const float* w_m    = (const float*)d_in[5];
  const float* b_m    = (const float*)d_in[6];
  const float* w_z    = (const float*)d_in[7];
  const float* b_z    = (const float*)d_in[8];
  const float* w_sa   = (const float*)d_in[9];
  const float* b_sa   = (const float*)d_in[10];
  const float* w_co   = (const float*)d_in[11];
  const float* b_co   = (const float*)d_in[12];
  float* out = (float*)d_out;

  float* ws  = (float*)d_ws;
  float* cT  = ws;                 // [4][1024][64] fp32 pixel-major
  float* mT  = ws + 262144;
  float* inp = ws + 524288;        // [4][1024]
  u16* ub   = (u16*)(ws + 528384);
  u16* hTb  = ub;                  // [4][1024][64] bf16
  u16* mTb  = ub + 262144;
  u16* xcat = ub + 524288;         // [4][1024][128]: Z | hc
  u16* qT   = ub + 1048576;        // [4][1024][64]
  u16* kT   = ub + 1310720;
  u16* mkT  = ub + 1572864;
  u16* vC   = ub + 1835008;        // [4][64][1024]
  u16* mvC  = ub + 2097152;
  u16* zT   = ub + 2359296;        // [4][1024][128]
  u16* Wg   = ub + 2883584;        // [19][256][32]
  u16* Whm  = ub + 3039232;        // [2][320][32]
  u16* Wzp  = ub + 3059712;        // [4][64][32]
  u16* Wsap = ub + 3067904;        // [36][192][32]

  hipMemsetAsync(ws, 0, (size_t)524288*4, stream);        // cT, mT = 0
  hipMemsetAsync(hTb, 0, (size_t)524288*2, stream);       // hTb, mTb = 0
  k_prep<<<dim3(1584), 256, 0, stream>>>(w_conv, w_h, w_m, w_z, w_sa, Wg, Whm, Wzp, Wsap);

  auto cell = [&](const float* xsrc, int xbs) {
    k_gates<<<dim3(16,4), 256, 0, stream>>>(hTb, xsrc, xbs, Wg, b_conv, cT, xcat);
    k_1x1<<<dim3(16,4), 256, 0, stream>>>(xcat, mTb, Whm, b_h, b_m, qT, kT, mkT, vC, mvC);
    k_attn2<<<dim3(16,2,4), 256, 0, stream>>>(qT, kT, mkT, vC, mvC, zT);
    k_z<<<dim3(16,4), 256, 0, stream>>>(zT, Wzp, b_z, xcat);
    k_sa<<<dim3(16,4), 256, 0, stream>>>(xcat, Wsap, b_sa, mT, mTb, hTb);
  };

  for (int t = 0; t < 10; ++t) cell(x + (size_t)t*SS, 10*SS);

  k_out2<<<dim3(4,4), 256, 0, stream>>>(hTb, w_co, b_co, inp, out, 0, 0);
  for (int j = 0; j < 10; ++j) {
    cell(inp, SS);
    k_out2<<<dim3(4,4), 256, 0, stream>>>(hTb, w_co, b_co, inp, out, 1, j);
  }
}

// Round 8
// 1227.738 us; speedup vs baseline: 5.3144x; 1.6253x over previous
//
#include <hip/hip_runtime.h>
#include <math.h>

// SAConvLSTM: all-MFMA implicit-GEMM convs + flash attention, pixel-major bf16.
// Round 8: 256-block grids everywhere + branch-free clamped/masked loads.
// Shapes: B=4, T=10, Ci=1, Hd=64, H=W=32, S=1024, future=10.
#define SS 1024

typedef unsigned short u16;
typedef __attribute__((ext_vector_type(8))) __bf16 bf16x8;
typedef __attribute__((ext_vector_type(4))) float f32x4;

#define MFMA(a,b,c) __builtin_amdgcn_mfma_f32_16x16x32_bf16(a,b,c,0,0,0)

__device__ __forceinline__ float sigm(float x){ return 1.f/(1.f+__expf(-x)); }
__device__ __forceinline__ u16 f2b(float x){ return __builtin_bit_cast(u16,(__bf16)x); }
__device__ __forceinline__ float b2f(u16 u){ return (float)__builtin_bit_cast(__bf16,u); }
__device__ __forceinline__ bf16x8 ldb8(const u16* p){ return *(const bf16x8*)p; }
__device__ __forceinline__ void st4b(u16* p, const f32x4 v){
  union { u16 u[4]; uint2 w; } t;
  t.u[0]=f2b(v[0]); t.u[1]=f2b(v[1]); t.u[2]=f2b(v[2]); t.u[3]=f2b(v[3]);
  *(uint2*)p = t.w;
}

// ---------------------------------------------------------------------------
// Weight prepack (unchanged). bf16 A-tiles [step][co][32].
// ---------------------------------------------------------------------------
__global__ __launch_bounds__(256) void k_prep(
    const float* __restrict__ wconv, const float* __restrict__ wh,
    const float* __restrict__ wm, const float* __restrict__ wz,
    const float* __restrict__ wsa,
    u16* __restrict__ Wg, u16* __restrict__ Whm,
    u16* __restrict__ Wzp, u16* __restrict__ Wsap)
{
  const int idx = blockIdx.x*256 + threadIdx.x;
  if (idx < 155648) {                       // 19*256*32
    const int step = idx >> 13, co = (idx >> 5) & 255, j = idx & 31;
    float v = 0.f;
    if (step < 18) {
      const int tap = step >> 1, ci = 1 + (step & 1)*32 + j;
      v = wconv[co*585 + ci*9 + tap];
    } else if (j < 9) {
      v = wconv[co*585 + j];                // ci=0 (x), tap j
    }
    Wg[idx] = f2b(v);
    return;
  }
  int l = idx - 155648;
  if (l < 20480) {                          // 2*320*32
    const int step = l / 10240, row = (l >> 5) % 320, j = l & 31;
    const int ci = step*32 + j;
    const float v = (row < 192) ? wh[row*64+ci]*(row < 64 ? 0.125f : 1.f)
                                : wm[(row-192)*64+ci];
    Whm[l] = f2b(v);
    return;
  }
  l -= 20480;
  if (l < 8192) {                           // 4*64*32
    const int step = l >> 11, co = (l >> 5) & 63, j = l & 31;
    Wzp[l] = f2b(wz[co*128 + step*32 + j]);
    return;
  }
  l -= 8192;
  if (l < 221184) {                         // 36*192*32
    const int step = l / 6144, co = (l >> 5) % 192, j = l & 31;
    const int tap = step >> 2, ci = (step & 3)*32 + j;
    Wsap[l] = f2b(wsa[(co*128+ci)*9 + tap]);
  }
}

// ---------------------------------------------------------------------------
// K1: conv3x3(concat(x,h)) -> gates -> c update, hc -> xcat.
// grid (64,4) block 256. Block: 16 px; wave: 4 co-tiles x 1 s-tile.
// ---------------------------------------------------------------------------
__global__ __launch_bounds__(256) void k_gates(
    const u16* __restrict__ hTb, const float* __restrict__ xsrc, int xbs,
    const u16* __restrict__ Wg, const float* __restrict__ bconv,
    float* __restrict__ cT, u16* __restrict__ xcat)
{
  const int b = blockIdx.y, s0 = blockIdx.x*16;
  const int tid = threadIdx.x, wid = tid>>6, lane = tid&63, gl = lane>>4, n = lane&15;
  const u16* hb = hTb + (size_t)b*SS*64;
  const int s = s0 + n, y = s>>5, x = s&31;
  f32x4 acc[4];
#pragma unroll
  for (int g4 = 0; g4 < 4; ++g4) {
    const int co = g4*64 + wid*16 + gl*4;
    acc[g4] = (f32x4){ bconv[co], bconv[co+1], bconv[co+2], bconv[co+3] };
  }
  // x-patch B-fragment (k = taps 0..8, padded to 32)
  bf16x8 xb;
  {
    union { u16 u[8]; bf16x8 v; } t;
#pragma unroll
    for (int j = 0; j < 8; ++j) t.u[j] = 0;
    if (gl == 0) {
#pragma unroll
      for (int j = 0; j < 8; ++j) {
        const int dy = j/3 - 1, dx = j%3 - 1;
        if ((unsigned)(y+dy) < 32u && (unsigned)(x+dx) < 32u)
          t.u[j] = f2b(xsrc[b*xbs + s + dy*32 + dx]);
      }
    } else if (gl == 1) {
      if (y+1 < 32 && x+1 < 32) t.u[0] = f2b(xsrc[b*xbs + s + 33]);
    }
    xb = t.v;
  }
#pragma unroll
  for (int step = 0; step < 18; ++step) {
    const int tap = step>>1, half = step&1;
    const int dy = tap/3 - 1, dx = tap%3 - 1;
    const bool ok = ((unsigned)(y+dy) < 32u) & ((unsigned)(x+dx) < 32u);
    const int sc = ok ? (s + dy*32 + dx) : s;          // clamped, always valid
    bf16x8 bv = ldb8(hb + (size_t)sc*64 + half*32 + gl*8);
    bv = ok ? bv : (bf16x8){};                          // branch-free mask
#pragma unroll
    for (int g4 = 0; g4 < 4; ++g4) {
      const bf16x8 a = ldb8(Wg + step*8192 + (g4*64 + wid*16 + n)*32 + gl*8);
      acc[g4] = MFMA(a, bv, acc[g4]);
    }
  }
#pragma unroll
  for (int g4 = 0; g4 < 4; ++g4) {
    const bf16x8 a = ldb8(Wg + 18*8192 + (g4*64 + wid*16 + n)*32 + gl*8);
    acc[g4] = MFMA(a, xb, acc[g4]);
  }
  const int hd0 = wid*16 + gl*4;
  float* cp = cT + ((size_t)b*SS + s)*64 + hd0;
  f32x4 cv = *(f32x4*)cp, hcv;
#pragma unroll
  for (int rr = 0; rr < 4; ++rr) {
    const float cn = sigm(acc[1][rr])*cv[rr] + sigm(acc[0][rr])*tanhf(acc[3][rr]);
    cv[rr] = cn;
    hcv[rr] = sigm(acc[2][rr])*tanhf(cn);
  }
  *(f32x4*)cp = cv;
  st4b(xcat + ((size_t)b*SS + s)*128 + 64 + hd0, hcv);
}

// ---------------------------------------------------------------------------
// K2: all 1x1 convs. grid (64,4) block 256; wave: 5 slices x 1 s-tile.
// ---------------------------------------------------------------------------
__global__ __launch_bounds__(256) void k_1x1(
    const u16* __restrict__ xcat, const u16* __restrict__ mTb,
    const u16* __restrict__ Whm, const float* __restrict__ bh,
    const float* __restrict__ bm,
    u16* __restrict__ qT, u16* __restrict__ kT, u16* __restrict__ mkT,
    u16* __restrict__ vC, u16* __restrict__ mvC)
{
  const int b = blockIdx.y, s0 = blockIdx.x*16;
  const int tid = threadIdx.x, wid = tid>>6, lane = tid&63, gl = lane>>4, n = lane&15;
  const int r0 = wid*16, cb = r0 + gl*4;
  const int s = s0 + n;
  f32x4 acc[5];
  acc[0] = (f32x4){ bh[cb]*0.125f, bh[cb+1]*0.125f, bh[cb+2]*0.125f, bh[cb+3]*0.125f };
  acc[1] = (f32x4){ bh[64+cb], bh[64+cb+1], bh[64+cb+2], bh[64+cb+3] };
  acc[2] = (f32x4){ bh[128+cb], bh[128+cb+1], bh[128+cb+2], bh[128+cb+3] };
  acc[3] = (f32x4){ bm[cb], bm[cb+1], bm[cb+2], bm[cb+3] };
  acc[4] = (f32x4){ bm[64+cb], bm[64+cb+1], bm[64+cb+2], bm[64+cb+3] };
#pragma unroll
  for (int step = 0; step < 2; ++step) {
    const bf16x8 bhc = ldb8(xcat + ((size_t)b*SS+s)*128 + 64 + step*32 + gl*8);
    const bf16x8 bmm = ldb8(mTb + ((size_t)b*SS+s)*64 + step*32 + gl*8);
#pragma unroll
    for (int tt = 0; tt < 5; ++tt) {
      const bf16x8 a = ldb8(Whm + step*10240 + (tt*64 + r0 + n)*32 + gl*8);
      acc[tt] = MFMA(a, tt < 3 ? bhc : bmm, acc[tt]);
    }
  }
  const size_t ps = ((size_t)b*SS + s)*64 + cb;
  st4b(qT + ps, acc[0]);
  st4b(kT + ps, acc[1]);
  st4b(mkT + ps, acc[3]);
#pragma unroll
  for (int rr = 0; rr < 4; ++rr) {
    vC[((size_t)b*64 + cb + rr)*SS + s] = f2b(acc[2][rr]);
    mvC[((size_t)b*64 + cb + rr)*SS + s] = f2b(acc[4][rr]);
  }
}

// ---------------------------------------------------------------------------
// K3: MFMA flash attention. grid (32,2,4) block 128 (2 waves, 16 q each).
// ---------------------------------------------------------------------------
__global__ __launch_bounds__(128) void k_attn2(
    const u16* __restrict__ qT, const u16* __restrict__ kT,
    const u16* __restrict__ mkT, const u16* __restrict__ vC,
    const u16* __restrict__ mvC, u16* __restrict__ zT)
{
  __shared__ u16 ldsP[2*16*72];
  const int tid = threadIdx.x, wid = tid>>6, lane = tid&63, gl = lane>>4, n = lane&15;
  const int b = blockIdx.z, at = blockIdx.y, q0 = blockIdx.x*32 + wid*16;
  const u16* qb = qT + (size_t)b*SS*64;
  const u16* kb = (at ? mkT : kT) + (size_t)b*SS*64;
  const u16* vb = (at ? mvC : vC) + (size_t)b*64*SS;
  const bf16x8 bq0 = ldb8(qb + (size_t)(q0+n)*64 + gl*8);
  const bf16x8 bq1 = ldb8(qb + (size_t)(q0+n)*64 + 32 + gl*8);
  f32x4 o[4];
#pragma unroll
  for (int ct = 0; ct < 4; ++ct) o[ct] = (f32x4){0.f,0.f,0.f,0.f};
  float mrun = -1e30f, lrun = 0.f;
  u16* pb = ldsP + wid*1152 + n*72;

  for (int step = 0; step < 16; ++step) {
    const int t0 = step*64;
    f32x4 st4[4];
#pragma unroll
    for (int tt = 0; tt < 4; ++tt) {
      const u16* kr = kb + (size_t)(t0 + tt*16 + n)*64;
      f32x4 a = {0.f,0.f,0.f,0.f};
      a = MFMA(ldb8(kr + gl*8), bq0, a);
      a = MFMA(ldb8(kr + 32 + gl*8), bq1, a);
      st4[tt] = a;
    }
    float mt = -1e30f;
#pragma unroll
    for (int tt = 0; tt < 4; ++tt)
#pragma unroll
      for (int rr = 0; rr < 4; ++rr) mt = fmaxf(mt, st4[tt][rr]);
    mt = fmaxf(mt, __shfl_xor(mt, 16));
    mt = fmaxf(mt, __shfl_xor(mt, 32));
    const float mnew = fmaxf(mrun, mt);
    const float f = __expf(mrun - mnew);
    float ps = 0.f;
#pragma unroll
    for (int tt = 0; tt < 4; ++tt) {
      const float p0e = __expf(st4[tt][0]-mnew), p1e = __expf(st4[tt][1]-mnew);
      const float p2e = __expf(st4[tt][2]-mnew), p3e = __expf(st4[tt][3]-mnew);
      ps += (p0e + p1e) + (p2e + p3e);
      *(unsigned*)(pb + tt*16 + gl*4)     = (unsigned)f2b(p0e) | ((unsigned)f2b(p1e)<<16);
      *(unsigned*)(pb + tt*16 + gl*4 + 2) = (unsigned)f2b(p2e) | ((unsigned)f2b(p3e)<<16);
    }
    ps += __shfl_xor(ps, 16);
    ps += __shfl_xor(ps, 32);
    lrun = lrun*f + ps;
    mrun = mnew;
    float fr[4];
#pragma unroll
    for (int rr = 0; rr < 4; ++rr) fr[rr] = __shfl(f, gl*4 + rr);
#pragma unroll
    for (int ct = 0; ct < 4; ++ct)
#pragma unroll
      for (int rr = 0; rr < 4; ++rr) o[ct][rr] *= fr[rr];
    const bf16x8 pa0 = ldb8(pb + gl*8);
    const bf16x8 pa1 = ldb8(pb + 32 + gl*8);
#pragma unroll
    for (int ct = 0; ct < 4; ++ct) {
      const u16* vr = vb + (size_t)(ct*16 + n)*SS + t0;
      o[ct] = MFMA(pa0, ldb8(vr + gl*8), o[ct]);
      o[ct] = MFMA(pa1, ldb8(vr + 32 + gl*8), o[ct]);
    }
  }
  float invr[4];
#pragma unroll
  for (int rr = 0; rr < 4; ++rr) invr[rr] = 1.f / __shfl(lrun, gl*4 + rr);
#pragma unroll
  for (int ct = 0; ct < 4; ++ct)
#pragma unroll
    for (int rr = 0; rr < 4; ++rr)
      zT[((size_t)b*SS + q0 + gl*4 + rr)*128 + at*64 + ct*16 + n] = f2b(o[ct][rr]*invr[rr]);
}

// ---------------------------------------------------------------------------
// K4: conv_z 128->64. grid (64,4) block 256; wave wid = co-tile, 1 s-tile.
// ---------------------------------------------------------------------------
__global__ __launch_bounds__(256) void k_z(
    const u16* __restrict__ zT, const u16* __restrict__ Wzp,
    const float* __restrict__ bz, u16* __restrict__ xcat)
{
  const int b = blockIdx.y, s0 = blockIdx.x*16;
  const int tid = threadIdx.x, wid = tid>>6, lane = tid&63, gl = lane>>4, n = lane&15;
  const int s = s0 + n;
  const int co = wid*16 + gl*4;
  f32x4 acc = (f32x4){ bz[co], bz[co+1], bz[co+2], bz[co+3] };
#pragma unroll
  for (int step = 0; step < 4; ++step) {
    const bf16x8 bv = ldb8(zT + ((size_t)b*SS + s)*128 + step*32 + gl*8);
    const bf16x8 a = ldb8(Wzp + step*2048 + (wid*16 + n)*32 + gl*8);
    acc = MFMA(a, bv, acc);
  }
  st4b(xcat + ((size_t)b*SS + s)*128 + co, acc);
}

// ---------------------------------------------------------------------------
// K5: conv3x3(concat(Z,hc)) -> i2,g2,o2 -> m,h updates.
// grid (64,4) block 256; wave: 3 co-tiles x 1 s-tile; 36 K-steps.
// ---------------------------------------------------------------------------
__global__ __launch_bounds__(256) void k_sa(
    const u16* __restrict__ xcat, const u16* __restrict__ Wsap,
    const float* __restrict__ bsa,
    float* __restrict__ mT, u16* __restrict__ mTb, u16* __restrict__ hTb)
{
  const int b = blockIdx.y, s0 = blockIdx.x*16;
  const int tid = threadIdx.x, wid = tid>>6, lane = tid&63, gl = lane>>4, n = lane&15;
  const int hd0 = wid*16 + gl*4;
  const int s = s0 + n, y = s>>5, x = s&31;
  f32x4 acc[3];
#pragma unroll
  for (int i = 0; i < 3; ++i) {
    const int co = i*64 + hd0;
    acc[i] = (f32x4){ bsa[co], bsa[co+1], bsa[co+2], bsa[co+3] };
  }
#pragma unroll
  for (int step = 0; step < 36; ++step) {
    const int tap = step>>2, qq = step&3;
    const int dy = tap/3 - 1, dx = tap%3 - 1;
    const bool ok = ((unsigned)(y+dy) < 32u) & ((unsigned)(x+dx) < 32u);
    const int sc = ok ? (s + dy*32 + dx) : s;
    bf16x8 bv = ldb8(xcat + ((size_t)b*SS + sc)*128 + qq*32 + gl*8);
    bv = ok ? bv : (bf16x8){};
#pragma unroll
    for (int i = 0; i < 3; ++i) {
      const bf16x8 a = ldb8(Wsap + step*6144 + (i*64 + wid*16 + n)*32 + gl*8);
      acc[i] = MFMA(a, bv, acc[i]);
    }
  }
  float* mp = mT + ((size_t)b*SS + s)*64 + hd0;
  f32x4 mv4 = *(f32x4*)mp, hv;
#pragma unroll
  for (int rr = 0; rr < 4; ++rr) {
    const float i2 = sigm(acc[0][rr]);
    const float mn = i2*tanhf(acc[1][rr]) + (1.f - i2)*mv4[rr];
    mv4[rr] = mn;
    hv[rr] = sigm(acc[2][rr])*mn;
  }
  *(f32x4*)mp = mv4;
  st4b(mTb + ((size_t)b*SS + s)*64 + hd0, mv4);
  st4b(hTb + ((size_t)b*SS + s)*64 + hd0, hv);
}

// ---------------------------------------------------------------------------
// K6: conv_out 64->1 (+optional sigmoid). grid (4,4) block 256.
// ---------------------------------------------------------------------------
__global__ __launch_bounds__(256) void k_out2(
    const u16* __restrict__ hTb, const float* __restrict__ wco,
    const float* __restrict__ bco,
    float* __restrict__ inp, float* __restrict__ out, int dosig, int j)
{
  __shared__ float wsm[64];
  if (threadIdx.x < 64) wsm[threadIdx.x] = wco[threadIdx.x];
  __syncthreads();
  const int b = blockIdx.y;
  const int s = blockIdx.x*256 + threadIdx.x;
  const u16* hp = hTb + ((size_t)b*SS + s)*64;
  float acc = bco[0];
#pragma unroll
  for (int i = 0; i < 64; ++i) acc += b2f(hp[i]) * wsm[i];
  if (dosig) {
    acc = sigm(acc);
    out[((size_t)b*10 + j)*SS + s] = acc;
  }
  inp[b*SS + s] = acc;
}

// ---------------------------------------------------------------------------
extern "C" void kernel_launch(void* const* d_in, const int* in_sizes, int n_in,
                              void* d_out, int out_size, void* d_ws, size_t ws_size,
                              hipStream_t stream) {
  const float* x      = (const float*)d_in[0];
  const float* w_conv = (const float*)d_in[1];
  const float* b_conv = (const float*)d_in[2];
  const float* w_h    = (const float*)d_in[3];
  const float* b_h    = (const float*)d_in[4];
  const float* w_m    = (const float*)d_in[5];
  const float* b_m    = (const float*)d_in[6];
  const float* w_z    = (const float*)d_in[7];
  const float* b_z    = (const float*)d_in[8];
  const float* w_sa   = (const float*)d_in[9];
  const float* b_sa   = (const float*)d_in[10];
  const float* w_co   = (const float*)d_in[11];
  const float* b_co   = (const float*)d_in[12];
  float* out = (float*)d_out;

  float* ws  = (float*)d_ws;
  float* cT  = ws;                 // [4][1024][64] fp32 pixel-major
  float* mT  = ws + 262144;
  float* inp = ws + 524288;        // [4][1024]
  u16* ub   = (u16*)(ws + 528384);
  u16* hTb  = ub;                  // [4][1024][64] bf16
  u16* mTb  = ub + 262144;
  u16* xcat = ub + 524288;         // [4][1024][128]: Z | hc
  u16* qT   = ub + 1048576;        // [4][1024][64]
  u16* kT   = ub + 1310720;
  u16* mkT  = ub + 1572864;
  u16* vC   = ub + 1835008;        // [4][64][1024]
  u16* mvC  = ub + 2097152;
  u16* zT   = ub + 2359296;        // [4][1024][128]
  u16* Wg   = ub + 2883584;        // [19][256][32]
  u16* Whm  = ub + 3039232;        // [2][320][32]
  u16* Wzp  = ub + 3059712;        // [4][64][32]
  u16* Wsap = ub + 3067904;        // [36][192][32]

  hipMemsetAsync(ws, 0, (size_t)524288*4, stream);        // cT, mT = 0
  hipMemsetAsync(hTb, 0, (size_t)524288*2, stream);       // hTb, mTb = 0
  k_prep<<<dim3(1584), 256, 0, stream>>>(w_conv, w_h, w_m, w_z, w_sa, Wg, Whm, Wzp, Wsap);

  auto cell = [&](const float* xsrc, int xbs) {
    k_gates<<<dim3(64,4), 256, 0, stream>>>(hTb, xsrc, xbs, Wg, b_conv, cT, xcat);
    k_1x1<<<dim3(64,4), 256, 0, stream>>>(xcat, mTb, Whm, b_h, b_m, qT, kT, mkT, vC, mvC);
    k_attn2<<<dim3(32,2,4), 128, 0, stream>>>(qT, kT, mkT, vC, mvC, zT);
    k_z<<<dim3(64,4), 256, 0, stream>>>(zT, Wzp, b_z, xcat);
    k_sa<<<dim3(64,4), 256, 0, stream>>>(xcat, Wsap, b_sa, mT, mTb, hTb);
  };

  for (int t = 0; t < 10; ++t) cell(x + (size_t)t*SS, 10*SS);

  k_out2<<<dim3(4,4), 256, 0, stream>>>(hTb, w_co, b_co, inp, out, 0, 0);
  for (int j = 0; j < 10; ++j) {
    cell(inp, SS);
    k_out2<<<dim3(4,4), 256, 0, stream>>>(hTb, w_co, b_co, inp, out, 1, j);
  }
}

// Round 9
// 1072.062 us; speedup vs baseline: 6.0861x; 1.1452x over previous
//
#include <hip/hip_runtime.h>
#include <math.h>

// SAConvLSTM r9: 3 fused MFMA kernels per cell (gates+1x1 | attn+z | sa+out).
// Shapes: B=4, T=10, Ci=1, Hd=64, H=W=32, S=1024, future=10.
#define SS 1024

typedef unsigned short u16;
typedef __attribute__((ext_vector_type(8))) __bf16 bf16x8;
typedef __attribute__((ext_vector_type(4))) float f32x4;

#define MFMA(a,b,c) __builtin_amdgcn_mfma_f32_16x16x32_bf16(a,b,c,0,0,0)

__device__ __forceinline__ float sigm(float x){ return 1.f/(1.f+__expf(-x)); }
__device__ __forceinline__ u16 f2b(float x){ return __builtin_bit_cast(u16,(__bf16)x); }
__device__ __forceinline__ float b2f(u16 u){ return (float)__builtin_bit_cast(__bf16,u); }
__device__ __forceinline__ bf16x8 ldb8(const u16* p){ return *(const bf16x8*)p; }
__device__ __forceinline__ void st4b(u16* p, const f32x4 v){
  union { u16 u[4]; uint2 w; } t;
  t.u[0]=f2b(v[0]); t.u[1]=f2b(v[1]); t.u[2]=f2b(v[2]); t.u[3]=f2b(v[3]);
  *(uint2*)p = t.w;
}

// ---------------------------------------------------------------------------
// Weight prepack (unchanged from r8). bf16 A-tiles [step][co][32].
// ---------------------------------------------------------------------------
__global__ __launch_bounds__(256) void k_prep(
    const float* __restrict__ wconv, const float* __restrict__ wh,
    const float* __restrict__ wm, const float* __restrict__ wz,
    const float* __restrict__ wsa,
    u16* __restrict__ Wg, u16* __restrict__ Whm,
    u16* __restrict__ Wzp, u16* __restrict__ Wsap)
{
  const int idx = blockIdx.x*256 + threadIdx.x;
  if (idx < 155648) {                       // 19*256*32
    const int step = idx >> 13, co = (idx >> 5) & 255, j = idx & 31;
    float v = 0.f;
    if (step < 18) {
      const int tap = step >> 1, ci = 1 + (step & 1)*32 + j;
      v = wconv[co*585 + ci*9 + tap];
    } else if (j < 9) {
      v = wconv[co*585 + j];                // ci=0 (x), tap j
    }
    Wg[idx] = f2b(v);
    return;
  }
  int l = idx - 155648;
  if (l < 20480) {                          // 2*320*32
    const int step = l / 10240, row = (l >> 5) % 320, j = l & 31;
    const int ci = step*32 + j;
    const float v = (row < 192) ? wh[row*64+ci]*(row < 64 ? 0.125f : 1.f)
                                : wm[(row-192)*64+ci];
    Whm[l] = f2b(v);
    return;
  }
  l -= 20480;
  if (l < 8192) {                           // 4*64*32
    const int step = l >> 11, co = (l >> 5) & 63, j = l & 31;
    Wzp[l] = f2b(wz[co*128 + step*32 + j]);
    return;
  }
  l -= 8192;
  if (l < 221184) {                         // 36*192*32
    const int step = l / 6144, co = (l >> 5) % 192, j = l & 31;
    const int tap = step >> 2, ci = (step & 3)*32 + j;
    Wsap[l] = f2b(wsa[(co*128+ci)*9 + tap]);
  }
}

// ---------------------------------------------------------------------------
// K_A: conv3x3 gates -> c/hc update, then fused 1x1 convs (hc via LDS).
// grid (64,4) block 256.
// ---------------------------------------------------------------------------
__global__ __launch_bounds__(256) void k_A(
    const u16* __restrict__ hTb, const float* __restrict__ xsrc, int xbs,
    const u16* __restrict__ Wg, const float* __restrict__ bconv,
    float* __restrict__ cT, u16* __restrict__ xcat,
    const u16* __restrict__ mTb, const u16* __restrict__ Whm,
    const float* __restrict__ bh, const float* __restrict__ bm,
    u16* __restrict__ qT, u16* __restrict__ kT, u16* __restrict__ mkT,
    u16* __restrict__ vC, u16* __restrict__ mvC)
{
  __shared__ u16 hcl[16][72];               // hc handoff, padded (2-way banks)
  const int b = blockIdx.y, s0 = blockIdx.x*16;
  const int tid = threadIdx.x, wid = tid>>6, lane = tid&63, gl = lane>>4, n = lane&15;
  const u16* hb = hTb + (size_t)b*SS*64;
  const int s = s0 + n, y = s>>5, x = s&31;
  // ---- gates stage ----
  f32x4 acc[4];
#pragma unroll
  for (int g4 = 0; g4 < 4; ++g4) {
    const int co = g4*64 + wid*16 + gl*4;
    acc[g4] = (f32x4){ bconv[co], bconv[co+1], bconv[co+2], bconv[co+3] };
  }
  bf16x8 xb;
  {
    union { u16 u[8]; bf16x8 v; } t;
#pragma unroll
    for (int j = 0; j < 8; ++j) t.u[j] = 0;
    if (gl == 0) {
#pragma unroll
      for (int j = 0; j < 8; ++j) {
        const int dy = j/3 - 1, dx = j%3 - 1;
        if ((unsigned)(y+dy) < 32u && (unsigned)(x+dx) < 32u)
          t.u[j] = f2b(xsrc[b*xbs + s + dy*32 + dx]);
      }
    } else if (gl == 1) {
      if (y+1 < 32 && x+1 < 32) t.u[0] = f2b(xsrc[b*xbs + s + 33]);
    }
    xb = t.v;
  }
#pragma unroll
  for (int step = 0; step < 18; ++step) {
    const int tap = step>>1, half = step&1;
    const int dy = tap/3 - 1, dx = tap%3 - 1;
    const bool ok = ((unsigned)(y+dy) < 32u) & ((unsigned)(x+dx) < 32u);
    const int sc = ok ? (s + dy*32 + dx) : s;
    bf16x8 bv = ldb8(hb + (size_t)sc*64 + half*32 + gl*8);
    bv = ok ? bv : (bf16x8){};
#pragma unroll
    for (int g4 = 0; g4 < 4; ++g4) {
      const bf16x8 a = ldb8(Wg + step*8192 + (g4*64 + wid*16 + n)*32 + gl*8);
      acc[g4] = MFMA(a, bv, acc[g4]);
    }
  }
#pragma unroll
  for (int g4 = 0; g4 < 4; ++g4) {
    const bf16x8 a = ldb8(Wg + 18*8192 + (g4*64 + wid*16 + n)*32 + gl*8);
    acc[g4] = MFMA(a, xb, acc[g4]);
  }
  const int hd0 = wid*16 + gl*4;
  {
    float* cp = cT + ((size_t)b*SS + s)*64 + hd0;
    f32x4 cv = *(f32x4*)cp, hcv;
#pragma unroll
    for (int rr = 0; rr < 4; ++rr) {
      const float cn = sigm(acc[1][rr])*cv[rr] + sigm(acc[0][rr])*tanhf(acc[3][rr]);
      cv[rr] = cn;
      hcv[rr] = sigm(acc[2][rr])*tanhf(cn);
    }
    *(f32x4*)cp = cv;
    st4b(xcat + ((size_t)b*SS + s)*128 + 64 + hd0, hcv);
    st4b(&hcl[n][hd0], hcv);
  }
  __syncthreads();
  // ---- 1x1 stage (hc from LDS, m from global) ----
  const int r0 = wid*16, cb = r0 + gl*4;
  f32x4 a1[5];
  a1[0] = (f32x4){ bh[cb]*0.125f, bh[cb+1]*0.125f, bh[cb+2]*0.125f, bh[cb+3]*0.125f };
  a1[1] = (f32x4){ bh[64+cb], bh[64+cb+1], bh[64+cb+2], bh[64+cb+3] };
  a1[2] = (f32x4){ bh[128+cb], bh[128+cb+1], bh[128+cb+2], bh[128+cb+3] };
  a1[3] = (f32x4){ bm[cb], bm[cb+1], bm[cb+2], bm[cb+3] };
  a1[4] = (f32x4){ bm[64+cb], bm[64+cb+1], bm[64+cb+2], bm[64+cb+3] };
#pragma unroll
  for (int step = 0; step < 2; ++step) {
    const bf16x8 bhc = ldb8(&hcl[n][step*32 + gl*8]);
    const bf16x8 bmm = ldb8(mTb + ((size_t)b*SS+s)*64 + step*32 + gl*8);
#pragma unroll
    for (int tt = 0; tt < 5; ++tt) {
      const bf16x8 a = ldb8(Whm + step*10240 + (tt*64 + r0 + n)*32 + gl*8);
      a1[tt] = MFMA(a, tt < 3 ? bhc : bmm, a1[tt]);
    }
  }
  const size_t ps = ((size_t)b*SS + s)*64 + cb;
  st4b(qT + ps, a1[0]);
  st4b(kT + ps, a1[1]);
  st4b(mkT + ps, a1[3]);
#pragma unroll
  for (int rr = 0; rr < 4; ++rr) {
    vC[((size_t)b*64 + cb + rr)*SS + s] = f2b(a1[2][rr]);
    mvC[((size_t)b*64 + cb + rr)*SS + s] = f2b(a1[4][rr]);
  }
}

// ---------------------------------------------------------------------------
// K_B: flash attention (KV split across 2 waves per attn type) + fused conv_z.
// grid (64,4) block 256. wave wid: at = wid&1, kv = wid>>1; block = 16 queries.
// ---------------------------------------------------------------------------
__global__ __launch_bounds__(256) void k_B(
    const u16* __restrict__ qT, const u16* __restrict__ kT,
    const u16* __restrict__ mkT, const u16* __restrict__ vC,
    const u16* __restrict__ mvC,
    const u16* __restrict__ Wzp, const float* __restrict__ bz,
    u16* __restrict__ xcat)
{
  __shared__ u16 ldsP[4*16*72];
  __shared__ float oS[2][16][65];           // partner wave's O (at, q, c)
  __shared__ float mS[2][16], lS[2][16];
  __shared__ u16 zbuf[16][136];             // Z tile (q, 128ch), padded
  const int tid = threadIdx.x, wid = tid>>6, lane = tid&63, gl = lane>>4, n = lane&15;
  const int b = blockIdx.z ? 0 : blockIdx.y, s0 = blockIdx.x*16;  // (grid y only)
  const int at = wid & 1, kv = wid >> 1;
  const u16* qb = qT + (size_t)b*SS*64;
  const u16* kb = (at ? mkT : kT) + (size_t)b*SS*64;
  const u16* vb = (at ? mvC : vC) + (size_t)b*64*SS;
  const bf16x8 bq0 = ldb8(qb + (size_t)(s0+n)*64 + gl*8);
  const bf16x8 bq1 = ldb8(qb + (size_t)(s0+n)*64 + 32 + gl*8);
  f32x4 o[4];
#pragma unroll
  for (int ct = 0; ct < 4; ++ct) o[ct] = (f32x4){0.f,0.f,0.f,0.f};
  float mrun = -1e30f, lrun = 0.f;
  u16* pb = ldsP + wid*1152 + n*72;

  for (int step = 0; step < 8; ++step) {
    const int t0 = kv*512 + step*64;
    f32x4 st4[4];
#pragma unroll
    for (int tt = 0; tt < 4; ++tt) {
      const u16* kr = kb + (size_t)(t0 + tt*16 + n)*64;
      f32x4 a = {0.f,0.f,0.f,0.f};
      a = MFMA(ldb8(kr + gl*8), bq0, a);
      a = MFMA(ldb8(kr + 32 + gl*8), bq1, a);
      st4[tt] = a;
    }
    float mt = -1e30f;
#pragma unroll
    for (int tt = 0; tt < 4; ++tt)
#pragma unroll
      for (int rr = 0; rr < 4; ++rr) mt = fmaxf(mt, st4[tt][rr]);
    mt = fmaxf(mt, __shfl_xor(mt, 16));
    mt = fmaxf(mt, __shfl_xor(mt, 32));
    const float mnew = fmaxf(mrun, mt);
    const float f = __expf(mrun - mnew);
    float ps = 0.f;
#pragma unroll
    for (int tt = 0; tt < 4; ++tt) {
      const float p0e = __expf(st4[tt][0]-mnew), p1e = __expf(st4[tt][1]-mnew);
      const float p2e = __expf(st4[tt][2]-mnew), p3e = __expf(st4[tt][3]-mnew);
      ps += (p0e + p1e) + (p2e + p3e);
      *(unsigned*)(pb + tt*16 + gl*4)     = (unsigned)f2b(p0e) | ((unsigned)f2b(p1e)<<16);
      *(unsigned*)(pb + tt*16 + gl*4 + 2) = (unsigned)f2b(p2e) | ((unsigned)f2b(p3e)<<16);
    }
    ps += __shfl_xor(ps, 16);
    ps += __shfl_xor(ps, 32);
    lrun = lrun*f + ps;
    mrun = mnew;
    float fr[4];
#pragma unroll
    for (int rr = 0; rr < 4; ++rr) fr[rr] = __shfl(f, gl*4 + rr);
#pragma unroll
    for (int ct = 0; ct < 4; ++ct)
#pragma unroll
      for (int rr = 0; rr < 4; ++rr) o[ct][rr] *= fr[rr];
    const bf16x8 pa0 = ldb8(pb + gl*8);
    const bf16x8 pa1 = ldb8(pb + 32 + gl*8);
#pragma unroll
    for (int ct = 0; ct < 4; ++ct) {
      const u16* vr = vb + (size_t)(ct*16 + n)*SS + t0;
      o[ct] = MFMA(pa0, ldb8(vr + gl*8), o[ct]);
      o[ct] = MFMA(pa1, ldb8(vr + 32 + gl*8), o[ct]);
    }
  }
  // ---- merge KV halves (kv=1 publishes; kv=0 merges) ----
  if (kv == 1) {
#pragma unroll
    for (int ct = 0; ct < 4; ++ct)
#pragma unroll
      for (int rr = 0; rr < 4; ++rr) oS[at][gl*4+rr][ct*16+n] = o[ct][rr];
    if (gl == 0) { mS[at][n] = mrun; lS[at][n] = lrun; }
  }
  __syncthreads();
  if (kv == 0) {
    const float m1 = mS[at][n], l1 = lS[at][n];
    const float mm = fmaxf(mrun, m1);
    const float e0 = __expf(mrun - mm), e1 = __expf(m1 - mm);
    const float inv = 1.f / (lrun*e0 + l1*e1);
    const float a0 = e0*inv, a1v = e1*inv;
    float f0r[4], f1r[4];
#pragma unroll
    for (int rr = 0; rr < 4; ++rr) {
      f0r[rr] = __shfl(a0, gl*4 + rr);
      f1r[rr] = __shfl(a1v, gl*4 + rr);
    }
#pragma unroll
    for (int ct = 0; ct < 4; ++ct)
#pragma unroll
      for (int rr = 0; rr < 4; ++rr)
        zbuf[gl*4+rr][at*64 + ct*16 + n] =
            f2b(o[ct][rr]*f0r[rr] + oS[at][gl*4+rr][ct*16+n]*f1r[rr]);
  }
  __syncthreads();
  // ---- conv_z stage (from LDS) ----
  const int co = wid*16 + gl*4;
  f32x4 acc = (f32x4){ bz[co], bz[co+1], bz[co+2], bz[co+3] };
#pragma unroll
  for (int qq = 0; qq < 4; ++qq) {
    const bf16x8 bv = ldb8(&zbuf[n][qq*32 + gl*8]);
    const bf16x8 a = ldb8(Wzp + qq*2048 + (wid*16 + n)*32 + gl*8);
    acc = MFMA(a, bv, acc);
  }
  st4b(xcat + ((size_t)b*SS + s0 + n)*128 + co, acc);
}

// ---------------------------------------------------------------------------
// K_C: conv3x3 sa -> m,h updates; fused conv_out (mode>=0).
// grid (64,4) block 256. mode: -1 none, 0 inp only, 1 sigmoid->out[j]+inp.
// ---------------------------------------------------------------------------
__global__ __launch_bounds__(256) void k_C(
    const u16* __restrict__ xcat, const u16* __restrict__ Wsap,
    const float* __restrict__ bsa,
    float* __restrict__ mT, u16* __restrict__ mTb, u16* __restrict__ hTb,
    const float* __restrict__ wco, const float* __restrict__ bco,
    float* __restrict__ inp, float* __restrict__ out, int mode, int j)
{
  __shared__ float pool[16][17];
  const int b = blockIdx.y, s0 = blockIdx.x*16;
  const int tid = threadIdx.x, wid = tid>>6, lane = tid&63, gl = lane>>4, n = lane&15;
  const int hd0 = wid*16 + gl*4;
  const int s = s0 + n, y = s>>5, x = s&31;
  f32x4 acc[3];
#pragma unroll
  for (int i = 0; i < 3; ++i) {
    const int co = i*64 + hd0;
    acc[i] = (f32x4){ bsa[co], bsa[co+1], bsa[co+2], bsa[co+3] };
  }
#pragma unroll
  for (int step = 0; step < 36; ++step) {
    const int tap = step>>2, qq = step&3;
    const int dy = tap/3 - 1, dx = tap%3 - 1;
    const bool ok = ((unsigned)(y+dy) < 32u) & ((unsigned)(x+dx) < 32u);
    const int sc = ok ? (s + dy*32 + dx) : s;
    bf16x8 bv = ldb8(xcat + ((size_t)b*SS + sc)*128 + qq*32 + gl*8);
    bv = ok ? bv : (bf16x8){};
#pragma unroll
    for (int i = 0; i < 3; ++i) {
      const bf16x8 a = ldb8(Wsap + step*6144 + (i*64 + wid*16 + n)*32 + gl*8);
      acc[i] = MFMA(a, bv, acc[i]);
    }
  }
  float* mp = mT + ((size_t)b*SS + s)*64 + hd0;
  f32x4 mv4 = *(f32x4*)mp, hv;
#pragma unroll
  for (int rr = 0; rr < 4; ++rr) {
    const float i2 = sigm(acc[0][rr]);
    const float mn = i2*tanhf(acc[1][rr]) + (1.f - i2)*mv4[rr];
    mv4[rr] = mn;
    hv[rr] = sigm(acc[2][rr])*mn;
  }
  *(f32x4*)mp = mv4;
  st4b(mTb + ((size_t)b*SS + s)*64 + hd0, mv4);
  st4b(hTb + ((size_t)b*SS + s)*64 + hd0, hv);
  if (mode >= 0) {
    pool[n][wid*4 + gl] = hv[0]*wco[hd0] + hv[1]*wco[hd0+1]
                        + hv[2]*wco[hd0+2] + hv[3]*wco[hd0+3];
    __syncthreads();
    if (tid < 16) {
      float v = bco[0];
#pragma unroll
      for (int i = 0; i < 16; ++i) v += pool[tid][i];
      const int sp = s0 + tid;
      if (mode == 1) {
        v = sigm(v);
        out[((size_t)b*10 + j)*SS + sp] = v;
      }
      inp[b*SS + sp] = v;
    }
  }
}

// ---------------------------------------------------------------------------
extern "C" void kernel_launch(void* const* d_in, const int* in_sizes, int n_in,
                              void* d_out, int out_size, void* d_ws, size_t ws_size,
                              hipStream_t stream) {
  const float* x      = (const float*)d_in[0];
  const float* w_conv = (const float*)d_in[1];
  const float* b_conv = (const float*)d_in[2];
  const float* w_h    = (const float*)d_in[3];
  const float* b_h    = (const float*)d_in[4];
  const float* w_m    = (const float*)d_in[5];
  const float* b_m    = (const float*)d_in[6];
  const float* w_z    = (const float*)d_in[7];
  const float* b_z    = (const float*)d_in[8];
  const float* w_sa   = (const float*)d_in[9];
  const float* b_sa   = (const float*)d_in[10];
  const float* w_co   = (const float*)d_in[11];
  const float* b_co   = (const float*)d_in[12];
  float* out = (float*)d_out;

  float* ws  = (float*)d_ws;
  float* cT  = ws;                 // [4][1024][64] fp32 pixel-major
  float* mT  = ws + 262144;
  float* inp = ws + 524288;        // [4][1024]
  u16* ub   = (u16*)(ws + 528384);
  u16* hTb  = ub;                  // [4][1024][64] bf16
  u16* mTb  = ub + 262144;
  u16* xcat = ub + 524288;         // [4][1024][128]: Z | hc
  u16* qT   = ub + 1048576;        // [4][1024][64]
  u16* kT   = ub + 1310720;
  u16* mkT  = ub + 1572864;
  u16* vC   = ub + 1835008;        // [4][64][1024]
  u16* mvC  = ub + 2097152;
  u16* Wg   = ub + 2359296;        // [19][256][32]
  u16* Whm  = ub + 2514944;        // [2][320][32]
  u16* Wzp  = ub + 2535424;        // [4][64][32]
  u16* Wsap = ub + 2543616;        // [36][192][32]

  hipMemsetAsync(ws, 0, (size_t)524288*4, stream);        // cT, mT = 0
  hipMemsetAsync(hTb, 0, (size_t)524288*2, stream);       // hTb, mTb = 0
  k_prep<<<dim3(1584), 256, 0, stream>>>(w_conv, w_h, w_m, w_z, w_sa, Wg, Whm, Wzp, Wsap);

  auto cell = [&](const float* xsrc, int xbs, int mode, int j) {
    k_A<<<dim3(64,4), 256, 0, stream>>>(hTb, xsrc, xbs, Wg, b_conv, cT, xcat,
                                        mTb, Whm, b_h, b_m, qT, kT, mkT, vC, mvC);
    k_B<<<dim3(64,4), 256, 0, stream>>>(qT, kT, mkT, vC, mvC, Wzp, b_z, xcat);
    k_C<<<dim3(64,4), 256, 0, stream>>>(xcat, Wsap, b_sa, mT, mTb, hTb,
                                        w_co, b_co, inp, out, mode, j);
  };

  for (int t = 0; t < 10; ++t)
    cell(x + (size_t)t*SS, 10*SS, (t == 9) ? 0 : -1, 0);
  for (int j = 0; j < 10; ++j)
    cell(inp, SS, 1, j);
}